// Round 9
// baseline (427.638 us; speedup 1.0000x reference)
//
#include <hip/hip_runtime.h>
#include <hip/hip_bf16.h>

typedef unsigned short u16;
typedef unsigned int   u32;

#define B_N   256
#define S_N   512
#define BSN   (B_N * S_N)      // 131072 positions
#define MEMN  32
#define DKN   128
#define DVN   128
#define DSN   256

typedef __attribute__((ext_vector_type(8))) short bf16x8;
typedef __attribute__((ext_vector_type(4))) float f32x4;

// ---------- helpers ----------
__device__ __forceinline__ float bf2f(u16 u) {
  union { u32 i; float f; } v; v.i = ((u32)u) << 16; return v.f;
}
__device__ __forceinline__ u16 f2bf(float f) {
  union { float f; u32 i; } v; v.f = f;
  u32 x = v.i;
  x += 0x7fffu + ((x >> 16) & 1u);   // RNE
  return (u16)(x >> 16);
}
__device__ __forceinline__ u32 pack2(float a, float b) {
  return (u32)f2bf(a) | ((u32)f2bf(b) << 16);
}
__device__ __forceinline__ float sigmoid_fast(float x) { return 1.f / (1.f + __expf(-x)); }
__device__ __forceinline__ float tanh_fast(float x)    { return 1.f - 2.f / (__expf(2.f * x) + 1.f); }

#define GLOAD_LDS16(g, l)                                         \
  __builtin_amdgcn_global_load_lds(                               \
      (const __attribute__((address_space(1))) void*)(g),         \
      (__attribute__((address_space(3))) void*)(l), 16, 0, 0)

// ============================================================
// kPrep: transpose + bf16-convert weights; build concatenated BqT:
// BqT[n][k], n<32: key_mem[n][k]; n>=32: W_df1[k][n-32].   184320 elems.
// ============================================================
__global__ __launch_bounds__(256) void kPrep(
    const float* __restrict__ W_sum, const float* __restrict__ W_ab1,
    const float* __restrict__ W_er,  const float* __restrict__ W_ad,
    const float* __restrict__ key_mem, const float* __restrict__ W_df1,
    u16* __restrict__ WsumT, u16* __restrict__ Wab1T,
    u16* __restrict__ WerT,  u16* __restrict__ WaddT,
    u16* __restrict__ BqT)
{
  int e = blockIdx.x * 256 + threadIdx.x;
  if (e < 65536) {
    const int n = e >> 8, k = e & 255;
    WsumT[e] = f2bf(W_sum[k * 256 + n]);
  } else if (e < 131072) {
    e -= 65536;
    const int n = e >> 8, k = e & 255;
    Wab1T[e] = f2bf(W_ab1[k * 256 + n]);
  } else if (e < 147456) {
    e -= 131072;
    const int n = e >> 7, k = e & 127;
    WerT[e] = f2bf(W_er[k * 128 + n]);
  } else if (e < 163840) {
    e -= 147456;
    const int n = e >> 7, k = e & 127;
    WaddT[e] = f2bf(W_ad[k * 128 + n]);
  } else if (e < 184320) {
    e -= 163840;
    const int n = e >> 7, k = e & 127;
    BqT[e] = f2bf(n < 32 ? key_mem[n * 128 + k] : W_df1[k * 128 + (n - 32)]);
  }
}

// ============================================================
// kErAdd: MFMA GEMM. out = act(qae @ W + b), W pre-transposed bf16.
// grid (BSN/128, 2), block 256 (4 waves, 64x64 tiles). y: 0=erase, 1=add.
// ============================================================
__global__ __launch_bounds__(256) void kErAdd(
    const int* __restrict__ qa_data, const float* __restrict__ qa_table,
    const u16* __restrict__ WerT, const u16* __restrict__ WaddT,
    const float* __restrict__ b_er, const float* __restrict__ b_ad,
    u16* __restrict__ eras, u16* __restrict__ addb)
{
  __shared__ __align__(16) u16 As[4 * 128 * 32];   // [chunk][m][k'] 32 KB
  __shared__ __align__(16) u16 Bs[2 * 128 * 32];   // dbuf [n][k'] 16 KB
  const int tid = threadIdx.x;
  const int p0  = blockIdx.x * 128;
  const int sel = blockIdx.y;
  const u16*   Wt = sel ? WaddT : WerT;
  const float* bb = sel ? b_ad  : b_er;
  u16*       outp = sel ? addb  : eras;

  // ---- stage A: gather 128 rows of qa_table (f32 -> bf16), chunked layout
  {
    const int r = tid >> 1, h = tid & 1;
    const long base = (long)qa_data[p0 + r] * DVN + h * 64;
    #pragma unroll
    for (int g = 0; g < 8; ++g) {
      const int k0 = h * 64 + g * 8;
      const float4 fa = *(const float4*)(qa_table + base + g * 8);
      const float4 fb = *(const float4*)(qa_table + base + g * 8 + 4);
      uint4 pk;
      pk.x = pack2(fa.x, fa.y); pk.y = pack2(fa.z, fa.w);
      pk.z = pack2(fb.x, fb.y); pk.w = pack2(fb.z, fb.w);
      *(uint4*)(As + (k0 >> 5) * 4096 + r * 32 + (k0 & 31)) = pk;
    }
  }
  // ---- stage B chunk 0
  {
    #pragma unroll
    for (int u = 0; u < 2; ++u) {
      const int f = tid + 256 * u;           // 0..511
      const int n = f >> 2, j = f & 3;
      *(uint4*)(Bs + n * 32 + j * 8) = *(const uint4*)(Wt + n * 128 + j * 8);
    }
  }
  __syncthreads();

  const int lane = tid & 63, wave = tid >> 6;
  const int wr = (wave >> 1) * 64, wc = (wave & 1) * 64;
  const int c15 = lane & 15, q = lane >> 4;

  f32x4 acc[4][4];
  #pragma unroll
  for (int b = 0; b < 4; ++b) {
    const float bv = bb[wc + 16 * b + c15];
    #pragma unroll
    for (int a = 0; a < 4; ++a) acc[a][b] = (f32x4){bv, bv, bv, bv};
  }

  for (int c = 0; c < 4; ++c) {
    const int cur = c & 1;
    uint4 st[2];
    const bool more = (c + 1 < 4);
    if (more) {
      #pragma unroll
      for (int u = 0; u < 2; ++u) {
        const int f = tid + 256 * u;
        const int n = f >> 2, j = f & 3;
        st[u] = *(const uint4*)(Wt + n * 128 + (c + 1) * 32 + j * 8);
      }
    }
    bf16x8 af[4], bf[4];
    #pragma unroll
    for (int a = 0; a < 4; ++a)
      af[a] = *(const bf16x8*)(As + c * 4096 + (wr + 16 * a + c15) * 32 + q * 8);
    #pragma unroll
    for (int b = 0; b < 4; ++b)
      bf[b] = *(const bf16x8*)(Bs + cur * 4096 + (wc + 16 * b + c15) * 32 + q * 8);
    #pragma unroll
    for (int a = 0; a < 4; ++a)
      #pragma unroll
      for (int b = 0; b < 4; ++b)
        acc[a][b] = __builtin_amdgcn_mfma_f32_16x16x32_bf16(af[a], bf[b], acc[a][b], 0, 0, 0);
    if (more) {
      #pragma unroll
      for (int u = 0; u < 2; ++u) {
        const int f = tid + 256 * u;
        const int n = f >> 2, j = f & 3;
        *(uint4*)(Bs + (cur ^ 1) * 4096 + n * 32 + j * 8) = st[u];
      }
    }
    __syncthreads();
  }

  // ---- epilogue: activation + u16 stores
  const int colb = wc + c15;
  #pragma unroll
  for (int a = 0; a < 4; ++a) {
    #pragma unroll
    for (int r = 0; r < 4; ++r) {
      const int row = p0 + wr + 16 * a + 4 * q + r;
      u16* yp = outp + (long)row * DVN + colb;
      #pragma unroll
      for (int b = 0; b < 4; ++b) {
        const float v = sel ? tanh_fast(acc[a][b][r]) : sigmoid_fast(acc[a][b][r]);
        yp[16 * b] = f2bf(v);
      }
    }
  }
}

// ============================================================
// kSum: MFMA GEMM. summary = tanh(sin @ W_sum + b). K=256 (8 chunks).
// grid (BSN/128, 2: col half). LDS: A 64KB + B 16KB = 80KB.
// ============================================================
__global__ __launch_bounds__(256) void kSum(
    const u16* __restrict__ X, const u16* __restrict__ WsumT,
    const float* __restrict__ bias, u16* __restrict__ Y)
{
  __shared__ __align__(16) u16 As[8 * 128 * 32];   // 64 KB
  __shared__ __align__(16) u16 Bs[2 * 128 * 32];   // 16 KB
  const int tid = threadIdx.x;
  const int p0  = blockIdx.x * 128;
  const int j0  = blockIdx.y * 128;

  { // stage A (bf16 copy, chunked) — FULL K coverage: 4096 uint4
    #pragma unroll
    for (int u = 0; u < 16; ++u) {
      const int f = tid + 256 * u;           // 0..4095
      const int r = f >> 5, j = f & 31;      // r: row 0..127, j: k-octet 0..31
      const uint4 raw = *(const uint4*)(X + (long)(p0 + r) * DSN + j * 8);
      *(uint4*)(As + (j >> 2) * 4096 + r * 32 + (j & 3) * 8) = raw;
    }
  }
  { // stage B chunk 0
    #pragma unroll
    for (int u = 0; u < 2; ++u) {
      const int f = tid + 256 * u;
      const int n = f >> 2, j = f & 3;
      *(uint4*)(Bs + n * 32 + j * 8) = *(const uint4*)(WsumT + (j0 + n) * 256 + j * 8);
    }
  }
  __syncthreads();

  const int lane = tid & 63, wave = tid >> 6;
  const int wr = (wave >> 1) * 64, wc = (wave & 1) * 64;
  const int c15 = lane & 15, q = lane >> 4;

  f32x4 acc[4][4];
  #pragma unroll
  for (int b = 0; b < 4; ++b) {
    const float bv = bias[j0 + wc + 16 * b + c15];
    #pragma unroll
    for (int a = 0; a < 4; ++a) acc[a][b] = (f32x4){bv, bv, bv, bv};
  }

  for (int c = 0; c < 8; ++c) {
    const int cur = c & 1;
    uint4 st[2];
    const bool more = (c + 1 < 8);
    if (more) {
      #pragma unroll
      for (int u = 0; u < 2; ++u) {
        const int f = tid + 256 * u;
        const int n = f >> 2, j = f & 3;
        st[u] = *(const uint4*)(WsumT + (j0 + n) * 256 + (c + 1) * 32 + j * 8);
      }
    }
    bf16x8 af[4], bf[4];
    #pragma unroll
    for (int a = 0; a < 4; ++a)
      af[a] = *(const bf16x8*)(As + c * 4096 + (wr + 16 * a + c15) * 32 + q * 8);
    #pragma unroll
    for (int b = 0; b < 4; ++b)
      bf[b] = *(const bf16x8*)(Bs + cur * 4096 + (wc + 16 * b + c15) * 32 + q * 8);
    #pragma unroll
    for (int a = 0; a < 4; ++a)
      #pragma unroll
      for (int b = 0; b < 4; ++b)
        acc[a][b] = __builtin_amdgcn_mfma_f32_16x16x32_bf16(af[a], bf[b], acc[a][b], 0, 0, 0);
    if (more) {
      #pragma unroll
      for (int u = 0; u < 2; ++u) {
        const int f = tid + 256 * u;
        const int n = f >> 2, j = f & 3;
        *(uint4*)(Bs + (cur ^ 1) * 4096 + n * 32 + j * 8) = st[u];
      }
    }
    __syncthreads();
  }

  const int colb = j0 + wc + c15;
  #pragma unroll
  for (int a = 0; a < 4; ++a) {
    #pragma unroll
    for (int r = 0; r < 4; ++r) {
      const int row = p0 + wr + 16 * a + 4 * q + r;
      u16* yp = Y + (long)row * DSN + colb;
      #pragma unroll
      for (int b = 0; b < 4; ++b)
        yp[16 * b] = f2bf(tanh_fast(acc[a][b][r]));
    }
  }
}

// ============================================================
// kAb: MFMA GEMM + fused W_ab2 dot.
// ============================================================
__global__ __launch_bounds__(256) void kAb(
    const u16* __restrict__ X, const u16* __restrict__ Wab1T,
    const float* __restrict__ bias, const float* __restrict__ Wab2,
    float* __restrict__ part)
{
  __shared__ __align__(16) u16 As[8 * 128 * 32];
  __shared__ __align__(16) u16 Bs[2 * 128 * 32];
  const int tid = threadIdx.x;
  const int p0  = blockIdx.x * 128;
  const int j0  = blockIdx.y * 128;

  { // stage A — FULL K coverage: 4096 uint4
    #pragma unroll
    for (int u = 0; u < 16; ++u) {
      const int f = tid + 256 * u;
      const int r = f >> 5, j = f & 31;
      const uint4 raw = *(const uint4*)(X + (long)(p0 + r) * DSN + j * 8);
      *(uint4*)(As + (j >> 2) * 4096 + r * 32 + (j & 3) * 8) = raw;
    }
  }
  {
    #pragma unroll
    for (int u = 0; u < 2; ++u) {
      const int f = tid + 256 * u;
      const int n = f >> 2, j = f & 3;
      *(uint4*)(Bs + n * 32 + j * 8) = *(const uint4*)(Wab1T + (j0 + n) * 256 + j * 8);
    }
  }
  __syncthreads();

  const int lane = tid & 63, wave = tid >> 6;
  const int wr = (wave >> 1) * 64, wc = (wave & 1) * 64;
  const int c15 = lane & 15, q = lane >> 4;

  f32x4 acc[4][4];
  float w2v[4];
  #pragma unroll
  for (int b = 0; b < 4; ++b) {
    const int col = j0 + wc + 16 * b + c15;
    const float bv = bias[col];
    w2v[b] = Wab2[col];
    #pragma unroll
    for (int a = 0; a < 4; ++a) acc[a][b] = (f32x4){bv, bv, bv, bv};
  }

  for (int c = 0; c < 8; ++c) {
    const int cur = c & 1;
    uint4 st[2];
    const bool more = (c + 1 < 8);
    if (more) {
      #pragma unroll
      for (int u = 0; u < 2; ++u) {
        const int f = tid + 256 * u;
        const int n = f >> 2, j = f & 3;
        st[u] = *(const uint4*)(Wab1T + (j0 + n) * 256 + (c + 1) * 32 + j * 8);
      }
    }
    bf16x8 af[4], bf[4];
    #pragma unroll
    for (int a = 0; a < 4; ++a)
      af[a] = *(const bf16x8*)(As + c * 4096 + (wr + 16 * a + c15) * 32 + q * 8);
    #pragma unroll
    for (int b = 0; b < 4; ++b)
      bf[b] = *(const bf16x8*)(Bs + cur * 4096 + (wc + 16 * b + c15) * 32 + q * 8);
    #pragma unroll
    for (int a = 0; a < 4; ++a)
      #pragma unroll
      for (int b = 0; b < 4; ++b)
        acc[a][b] = __builtin_amdgcn_mfma_f32_16x16x32_bf16(af[a], bf[b], acc[a][b], 0, 0, 0);
    if (more) {
      #pragma unroll
      for (int u = 0; u < 2; ++u) {
        const int f = tid + 256 * u;
        const int n = f >> 2, j = f & 3;
        *(uint4*)(Bs + (cur ^ 1) * 4096 + n * 32 + j * 8) = st[u];
      }
    }
    __syncthreads();   // final barrier also fences Bs reuse below
  }

  // ---- epilogue: tanh, dot with W_ab2, reduce 16 col-lanes, pair waves
  float sv[4][4];
  #pragma unroll
  for (int a = 0; a < 4; ++a) {
    #pragma unroll
    for (int r = 0; r < 4; ++r) {
      float s = 0.f;
      #pragma unroll
      for (int b = 0; b < 4; ++b)
        s = fmaf(tanh_fast(acc[a][b][r]), w2v[b], s);
      s += __shfl_xor(s, 1, 64);
      s += __shfl_xor(s, 2, 64);
      s += __shfl_xor(s, 4, 64);
      s += __shfl_xor(s, 8, 64);
      sv[a][r] = s;
    }
  }
  float* red = (float*)Bs;   // 128 f32, reuse (fenced by loop's last barrier)
  if ((wave & 1) && c15 == 0) {
    #pragma unroll
    for (int a = 0; a < 4; ++a)
      #pragma unroll
      for (int r = 0; r < 4; ++r)
        red[wr + 16 * a + 4 * q + r] = sv[a][r];
  }
  __syncthreads();
  if (!(wave & 1) && c15 == 0) {
    #pragma unroll
    for (int a = 0; a < 4; ++a)
      #pragma unroll
      for (int r = 0; r < 4; ++r) {
        const int rr = wr + 16 * a + 4 * q + r;
        part[(long)blockIdx.y * BSN + p0 + rr] = sv[a][r] + red[rr];
      }
  }
}

// ============================================================
// kQe (MFMA): one GEMM qe[128x128] @ BqT^T[128x160] per block.
// cols 0..31 = attention scores -> softmax -> w_all
// cols 32..159 = df hidden -> tanh -> dot W_df2 -> diff
// qe -> sinb copy fused into A staging.
// ============================================================
__global__ __launch_bounds__(256) void kQe(
    const int* __restrict__ q_data, const float* __restrict__ q_table,
    const u16* __restrict__ BqT,
    const float* __restrict__ bdf1, const float* __restrict__ Wdf2,
    const float* __restrict__ bdf2,
    float* __restrict__ w_all, float* __restrict__ diff,
    u16* __restrict__ sin_buf)
{
  __shared__ __align__(16) u16 As[4 * 128 * 32];   // 32 KB [chunk][row][k']
  __shared__ __align__(16) u16 Bs[4 * 160 * 32];   // 40 KB [chunk][n][k']
  const int tid = threadIdx.x;
  const int p0  = blockIdx.x * 128;

  // ---- stage A: gather qe rows (f32->bf16), fused sinb store
  {
    const int r = tid >> 1, h = tid & 1;
    const long base = (long)q_data[p0 + r] * DKN + h * 64;
    #pragma unroll
    for (int g = 0; g < 8; ++g) {
      const int k0 = h * 64 + g * 8;
      const float4 fa = *(const float4*)(q_table + base + g * 8);
      const float4 fb = *(const float4*)(q_table + base + g * 8 + 4);
      uint4 pk;
      pk.x = pack2(fa.x, fa.y); pk.y = pack2(fa.z, fa.w);
      pk.z = pack2(fb.x, fb.y); pk.w = pack2(fb.z, fb.w);
      *(uint4*)(As + (k0 >> 5) * 4096 + r * 32 + (k0 & 31)) = pk;
      *(uint4*)(sin_buf + (long)(p0 + r) * DSN + DKN + k0) = pk;
    }
  }
  // ---- stage B: 160 rows x 128 k = 2560 uint4 (10/thread)
  {
    #pragma unroll
    for (int u = 0; u < 10; ++u) {
      const int f = tid + 256 * u;           // 0..2559
      const int n = f >> 4, jj = f & 15;
      *(uint4*)(Bs + (jj >> 2) * 5120 + n * 32 + (jj & 3) * 8) =
          *(const uint4*)(BqT + n * 128 + jj * 8);
    }
  }
  __syncthreads();

  const int lane = tid & 63, wave = tid >> 6;
  const int wr = (wave >> 1) * 64, wc = (wave & 1) * 80;
  const int c15 = lane & 15, q = lane >> 4;

  f32x4 acc[4][5];
  float w2v[5];
  #pragma unroll
  for (int b = 0; b < 5; ++b) {
    const int col = wc + 16 * b + c15;
    const float bv = (col < 32) ? 0.f : bdf1[col - 32];
    w2v[b] = (col < 32) ? 0.f : Wdf2[col - 32];
    #pragma unroll
    for (int a = 0; a < 4; ++a) acc[a][b] = (f32x4){bv, bv, bv, bv};
  }

  #pragma unroll
  for (int c = 0; c < 4; ++c) {
    bf16x8 af[4], bf[5];
    #pragma unroll
    for (int a = 0; a < 4; ++a)
      af[a] = *(const bf16x8*)(As + c * 4096 + (wr + 16 * a + c15) * 32 + q * 8);
    #pragma unroll
    for (int b = 0; b < 5; ++b)
      bf[b] = *(const bf16x8*)(Bs + c * 5120 + (wc + 16 * b + c15) * 32 + q * 8);
    #pragma unroll
    for (int a = 0; a < 4; ++a)
      #pragma unroll
      for (int b = 0; b < 5; ++b)
        acc[a][b] = __builtin_amdgcn_mfma_f32_16x16x32_bf16(af[a], bf[b], acc[a][b], 0, 0, 0);
  }

  // ---- softmax over cols 0..31 (waves with wc==0 only: b=0,1)
  if (wc == 0) {
    #pragma unroll
    for (int a = 0; a < 4; ++a) {
      #pragma unroll
      for (int r = 0; r < 4; ++r) {
        float s0 = acc[a][0][r], s1 = acc[a][1][r];
        float mx = fmaxf(s0, s1);
        mx = fmaxf(mx, __shfl_xor(mx, 1, 64));
        mx = fmaxf(mx, __shfl_xor(mx, 2, 64));
        mx = fmaxf(mx, __shfl_xor(mx, 4, 64));
        mx = fmaxf(mx, __shfl_xor(mx, 8, 64));
        const float e0 = __expf(s0 - mx), e1 = __expf(s1 - mx);
        float sm = e0 + e1;
        sm += __shfl_xor(sm, 1, 64);
        sm += __shfl_xor(sm, 2, 64);
        sm += __shfl_xor(sm, 4, 64);
        sm += __shfl_xor(sm, 8, 64);
        const float inv = 1.f / sm;
        const int row = p0 + wr + 16 * a + 4 * q + r;
        w_all[(long)row * MEMN + c15]      = e0 * inv;
        w_all[(long)row * MEMN + 16 + c15] = e1 * inv;
      }
    }
  }

  // ---- diff partials: tanh + W_df2 dot (w2v==0 masks attention cols)
  float sv[4][4];
  #pragma unroll
  for (int a = 0; a < 4; ++a) {
    #pragma unroll
    for (int r = 0; r < 4; ++r) {
      float s = 0.f;
      #pragma unroll
      for (int b = 0; b < 5; ++b)
        s = fmaf(tanh_fast(acc[a][b][r]), w2v[b], s);
      s += __shfl_xor(s, 1, 64);
      s += __shfl_xor(s, 2, 64);
      s += __shfl_xor(s, 4, 64);
      s += __shfl_xor(s, 8, 64);
      sv[a][r] = s;
    }
  }
  __syncthreads();               // all MFMA LDS reads done; reuse As
  float* red = (float*)As;       // 128 f32
  if ((wave & 1) && c15 == 0) {  // wc==80 waves
    #pragma unroll
    for (int a = 0; a < 4; ++a)
      #pragma unroll
      for (int r = 0; r < 4; ++r)
        red[wr + 16 * a + 4 * q + r] = sv[a][r];
  }
  __syncthreads();
  if (!(wave & 1) && c15 == 0) {
    const float bd = bdf2[0];
    #pragma unroll
    for (int a = 0; a < 4; ++a)
      #pragma unroll
      for (int r = 0; r < 4; ++r) {
        const int rr = wr + 16 * a + 4 * q + r;
        diff[p0 + rr] = sv[a][r] + red[rr] + bd;
      }
  }
}

// ============================================================
// kScan: column-owner sequential scan with async LDS operand staging.
// grid (B_N), block 128. Thread owns col c: Mv[32] in VGPRs.
// Per 32-step chunk: stage w(4KB)+e(8KB)+a(8KB) via global_load_lds
// (double-buffered, issued one full chunk ahead — compiler cannot sink).
// Per step: 8 broadcast ds_read_b128 (w) + 2 ds_read_u16 (e,a),
// prefetched one step ahead (even/odd reg sets). No shfl, no dup loads.
// FIX vs round 8: store index is the LOCAL step (sp already includes
// pbase) — round 8 double-counted pbase, scattering reads out of place.
// ============================================================
#define CHUNK_BYTES 20480
#define KSTEP(W, E, A, SLOC)                                    \
  {                                                             \
    float ac0 = 0.f, ac1 = 0.f, ac2 = 0.f, ac3 = 0.f;           \
    _Pragma("unroll")                                           \
    for (int i = 0; i < 8; ++i) {                               \
      ac0 = fmaf(W[i][0], Mv[4 * i + 0], ac0);                  \
      ac1 = fmaf(W[i][1], Mv[4 * i + 1], ac1);                  \
      ac2 = fmaf(W[i][2], Mv[4 * i + 2], ac2);                  \
      ac3 = fmaf(W[i][3], Mv[4 * i + 3], ac3);                  \
    }                                                           \
    sp[(long)(SLOC) * DSN] = f2bf((ac0 + ac1) + (ac2 + ac3));   \
    const float ec = bf2f(E);                                   \
    const float an = -bf2f(A);                                  \
    _Pragma("unroll")                                           \
    for (int i = 0; i < 8; ++i) {                               \
      _Pragma("unroll")                                         \
      for (int j = 0; j < 4; ++j) {                             \
        const float t = fmaf(ec, Mv[4 * i + j], an);            \
        Mv[4 * i + j] = fmaf(-W[i][j], t, Mv[4 * i + j]);       \
      }                                                         \
    }                                                           \
  }

#define KSTAGE(K, BUF)                                                        \
  {                                                                           \
    const char* wsrc = (const char*)(w_all + (pbase + (long)(K) * 32) * MEMN);\
    const char* esrc = (const char*)(eras + (pbase + (long)(K) * 32) * DVN);  \
    const char* asrc = (const char*)(addb + (pbase + (long)(K) * 32) * DVN);  \
    char* dst = lds + (BUF) * CHUNK_BYTES;                                    \
    _Pragma("unroll")                                                         \
    for (int r = 0; r < 10; ++r) {                                            \
      const int o = (tid + r * 128) * 16;                                     \
      const char* src = (o < 4096) ? (wsrc + o)                               \
                      : (o < 12288) ? (esrc + (o - 4096))                     \
                                    : (asrc + (o - 12288));                   \
      GLOAD_LDS16(src, dst + o);                                              \
    }                                                                         \
  }

__global__ __launch_bounds__(128, 2) void kScan(
    const float* __restrict__ w_all, const u16* __restrict__ eras,
    const u16* __restrict__ addb, const float* __restrict__ init_mem,
    u16* __restrict__ sin_buf)
{
  __shared__ __align__(16) char lds[2 * CHUNK_BYTES + 256];   // +pad for junk prefetch
  const int tid = threadIdx.x;
  const int c = tid;
  const long pbase = (long)blockIdx.x * S_N;

  float Mv[32];
  #pragma unroll
  for (int m = 0; m < 32; ++m) Mv[m] = init_mem[m * DVN + c];

  u16* sp = sin_buf + pbase * DSN + c;

  KSTAGE(0, 0)
  for (int k = 0; k < 16; ++k) {
    __syncthreads();                       // chunk k staged; buf (k+1)&1 free
    if (k + 1 < 16) KSTAGE(k + 1, (k + 1) & 1)

    const char* wb = lds + (k & 1) * CHUNK_BYTES;
    const f32x4* wl = (const f32x4*)wb;            // [32 steps][8 f32x4]
    const u16*   el = (const u16*)(wb + 4096);     // [32][128]
    const u16*   al = (const u16*)(wb + 12288);    // [32][128]
    const int lb = k * 32;                         // local step base

    f32x4 WA[8], WB[8];
    u16 eA, aA, eB, aB;
    #pragma unroll
    for (int i = 0; i < 8; ++i) WA[i] = wl[i];
    eA = el[c]; aA = al[c];

    #pragma unroll 1
    for (int s = 0; s < 32; s += 2) {
      #pragma unroll
      for (int i = 0; i < 8; ++i) WB[i] = wl[(s + 1) * 8 + i];
      eB = el[(s + 1) * 128 + c]; aB = al[(s + 1) * 128 + c];
      KSTEP(WA, eA, aA, lb + s)
      #pragma unroll
      for (int i = 0; i < 8; ++i) WA[i] = wl[(s + 2) * 8 + i];  // s=30: junk, unused
      eA = el[(s + 2) * 128 + c]; aA = al[(s + 2) * 128 + c];   // s=30: junk (pad)
      KSTEP(WB, eB, aB, lb + s + 1)
    }
  }
}

// ============================================================
// kOut: combine. grid (BSN/256), block 256. f32 output.
// ============================================================
__global__ __launch_bounds__(256) void kOut(
    const float* __restrict__ part, const float* __restrict__ diff,
    const float* __restrict__ bab2, float* __restrict__ out)
{
  const int p = blockIdx.x * 256 + threadIdx.x;
  const float ab = part[p] + part[BSN + p] + bab2[0];
  const float d  = diff[p];
  const float z  = 3.0f * ab - d;
  out[p]           = sigmoid_fast(z);
  out[BSN + p]     = ab;
  out[2 * BSN + p] = d;
  out[3 * BSN + p] = z;
}

// ============================================================
// launch
// ============================================================
extern "C" void kernel_launch(void* const* d_in, const int* in_sizes, int n_in,
                              void* d_out, int out_size, void* d_ws, size_t ws_size,
                              hipStream_t stream)
{
  const int*   q_data   = (const int*)d_in[0];
  const int*   qa_data  = (const int*)d_in[1];
  const float* q_table  = (const float*)d_in[2];
  const float* qa_table = (const float*)d_in[3];
  const float* key_mem  = (const float*)d_in[4];
  const float* init_mem = (const float*)d_in[5];
  const float* W_erase  = (const float*)d_in[6];
  const float* b_erase  = (const float*)d_in[7];
  const float* W_add    = (const float*)d_in[8];
  const float* b_add    = (const float*)d_in[9];
  const float* W_sum    = (const float*)d_in[10];
  const float* b_sum    = (const float*)d_in[11];
  const float* W_ab1    = (const float*)d_in[12];
  const float* b_ab1    = (const float*)d_in[13];
  const float* W_ab2    = (const float*)d_in[14];
  const float* b_ab2    = (const float*)d_in[15];
  const float* W_df1    = (const float*)d_in[16];
  const float* b_df1    = (const float*)d_in[17];
  const float* W_df2    = (const float*)d_in[18];
  const float* b_df2    = (const float*)d_in[19];

  // workspace layout (bytes); total 152,936,448
  char* ws = (char*)d_ws;
  float* w_all = (float*)(ws + 0);           // [BS][32] f32   16,777,216
  u16*   eras  = (u16*)(ws + 16777216);      // [BS][128] bf16 33,554,432
  u16*   addb  = (u16*)(ws + 50331648);      // [BS][128] bf16 33,554,432
  u16*   sinb  = (u16*)(ws + 83886080);      // [BS][256] bf16 67,108,864
  float* diffb = (float*)(ws + 150994944);   // [BS] f32          524,288
  float* part  = (float*)(ws + 151519232);   // [2][BS] f32     1,048,576
  u16*   WerT  = (u16*)(ws + 152567808);     // 32,768
  u16*   WaddT = (u16*)(ws + 152600576);     // 32,768
  u16*   WsumT = (u16*)(ws + 152633344);     // 131,072
  u16*   Wab1T = (u16*)(ws + 152764416);     // 131,072
  u16*   BqT   = (u16*)(ws + 152895488);     // 160x128 bf16 = 40,960
  u16*   summ  = eras;                       // summary reuses eras+addb

  kPrep<<<dim3(720), 256, 0, stream>>>(W_sum, W_ab1, W_erase, W_add, key_mem, W_df1,
                                       WsumT, Wab1T, WerT, WaddT, BqT);
  kErAdd<<<dim3(BSN / 128, 2), 256, 0, stream>>>(qa_data, qa_table, WerT, WaddT,
                                                 b_erase, b_add, eras, addb);
  kQe<<<dim3(BSN / 128), 256, 0, stream>>>(q_data, q_table, BqT, b_df1, W_df2, b_df2,
                                           w_all, diffb, sinb);
  kScan<<<dim3(B_N), 128, 0, stream>>>(w_all, eras, addb, init_mem, sinb);
  kSum<<<dim3(BSN / 128, 2), 256, 0, stream>>>(sinb, WsumT, b_sum, summ);
  kAb<<<dim3(BSN / 128, 2), 256, 0, stream>>>(summ, Wab1T, b_ab1, W_ab2, part);
  kOut<<<dim3(BSN / 256), 256, 0, stream>>>(part, diffb, b_ab2, (float*)d_out);
}

// Round 10
// 379.170 us; speedup vs baseline: 1.1278x; 1.1278x over previous
//
#include <hip/hip_runtime.h>
#include <hip/hip_bf16.h>

typedef unsigned short u16;
typedef unsigned int   u32;

#define B_N   256
#define S_N   512
#define BSN   (B_N * S_N)      // 131072 positions
#define MEMN  32
#define DKN   128
#define DVN   128
#define DSN   256

typedef __attribute__((ext_vector_type(8))) short bf16x8;
typedef __attribute__((ext_vector_type(4))) float f32x4;

// ---------- helpers ----------
__device__ __forceinline__ float bf2f(u16 u) {
  union { u32 i; float f; } v; v.i = ((u32)u) << 16; return v.f;
}
__device__ __forceinline__ u16 f2bf(float f) {
  union { float f; u32 i; } v; v.f = f;
  u32 x = v.i;
  x += 0x7fffu + ((x >> 16) & 1u);   // RNE
  return (u16)(x >> 16);
}
__device__ __forceinline__ u32 pack2(float a, float b) {
  return (u32)f2bf(a) | ((u32)f2bf(b) << 16);
}
__device__ __forceinline__ float sigmoid_fast(float x) { return 1.f / (1.f + __expf(-x)); }
__device__ __forceinline__ float tanh_fast(float x)    { return 1.f - 2.f / (__expf(2.f * x) + 1.f); }

#define GLOAD_LDS16(g, l)                                         \
  __builtin_amdgcn_global_load_lds(                               \
      (const __attribute__((address_space(1))) void*)(g),         \
      (__attribute__((address_space(3))) void*)(l), 16, 0, 0)

// ============================================================
// kPrep: transpose + bf16-convert weights; build concatenated BqT:
// BqT[n][k], n<32: key_mem[n][k]; n>=32: W_df1[k][n-32].   184320 elems.
// ============================================================
__global__ __launch_bounds__(256) void kPrep(
    const float* __restrict__ W_sum, const float* __restrict__ W_ab1,
    const float* __restrict__ W_er,  const float* __restrict__ W_ad,
    const float* __restrict__ key_mem, const float* __restrict__ W_df1,
    u16* __restrict__ WsumT, u16* __restrict__ Wab1T,
    u16* __restrict__ WerT,  u16* __restrict__ WaddT,
    u16* __restrict__ BqT)
{
  int e = blockIdx.x * 256 + threadIdx.x;
  if (e < 65536) {
    const int n = e >> 8, k = e & 255;
    WsumT[e] = f2bf(W_sum[k * 256 + n]);
  } else if (e < 131072) {
    e -= 65536;
    const int n = e >> 8, k = e & 255;
    Wab1T[e] = f2bf(W_ab1[k * 256 + n]);
  } else if (e < 147456) {
    e -= 131072;
    const int n = e >> 7, k = e & 127;
    WerT[e] = f2bf(W_er[k * 128 + n]);
  } else if (e < 163840) {
    e -= 147456;
    const int n = e >> 7, k = e & 127;
    WaddT[e] = f2bf(W_ad[k * 128 + n]);
  } else if (e < 184320) {
    e -= 163840;
    const int n = e >> 7, k = e & 127;
    BqT[e] = f2bf(n < 32 ? key_mem[n * 128 + k] : W_df1[k * 128 + (n - 32)]);
  }
}

// ============================================================
// kErAdd: MFMA GEMM. out = act(qae @ W + b), W pre-transposed bf16.
// grid (BSN/128, 2), block 256 (4 waves, 64x64 tiles). y: 0=erase, 1=add.
// ============================================================
__global__ __launch_bounds__(256) void kErAdd(
    const int* __restrict__ qa_data, const float* __restrict__ qa_table,
    const u16* __restrict__ WerT, const u16* __restrict__ WaddT,
    const float* __restrict__ b_er, const float* __restrict__ b_ad,
    u16* __restrict__ eras, u16* __restrict__ addb)
{
  __shared__ __align__(16) u16 As[4 * 128 * 32];   // [chunk][m][k'] 32 KB
  __shared__ __align__(16) u16 Bs[2 * 128 * 32];   // dbuf [n][k'] 16 KB
  const int tid = threadIdx.x;
  const int p0  = blockIdx.x * 128;
  const int sel = blockIdx.y;
  const u16*   Wt = sel ? WaddT : WerT;
  const float* bb = sel ? b_ad  : b_er;
  u16*       outp = sel ? addb  : eras;

  // ---- stage A: gather 128 rows of qa_table (f32 -> bf16), chunked layout
  {
    const int r = tid >> 1, h = tid & 1;
    const long base = (long)qa_data[p0 + r] * DVN + h * 64;
    #pragma unroll
    for (int g = 0; g < 8; ++g) {
      const int k0 = h * 64 + g * 8;
      const float4 fa = *(const float4*)(qa_table + base + g * 8);
      const float4 fb = *(const float4*)(qa_table + base + g * 8 + 4);
      uint4 pk;
      pk.x = pack2(fa.x, fa.y); pk.y = pack2(fa.z, fa.w);
      pk.z = pack2(fb.x, fb.y); pk.w = pack2(fb.z, fb.w);
      *(uint4*)(As + (k0 >> 5) * 4096 + r * 32 + (k0 & 31)) = pk;
    }
  }
  // ---- stage B chunk 0
  {
    #pragma unroll
    for (int u = 0; u < 2; ++u) {
      const int f = tid + 256 * u;           // 0..511
      const int n = f >> 2, j = f & 3;
      *(uint4*)(Bs + n * 32 + j * 8) = *(const uint4*)(Wt + n * 128 + j * 8);
    }
  }
  __syncthreads();

  const int lane = tid & 63, wave = tid >> 6;
  const int wr = (wave >> 1) * 64, wc = (wave & 1) * 64;
  const int c15 = lane & 15, q = lane >> 4;

  f32x4 acc[4][4];
  #pragma unroll
  for (int b = 0; b < 4; ++b) {
    const float bv = bb[wc + 16 * b + c15];
    #pragma unroll
    for (int a = 0; a < 4; ++a) acc[a][b] = (f32x4){bv, bv, bv, bv};
  }

  for (int c = 0; c < 4; ++c) {
    const int cur = c & 1;
    uint4 st[2];
    const bool more = (c + 1 < 4);
    if (more) {
      #pragma unroll
      for (int u = 0; u < 2; ++u) {
        const int f = tid + 256 * u;
        const int n = f >> 2, j = f & 3;
        st[u] = *(const uint4*)(Wt + n * 128 + (c + 1) * 32 + j * 8);
      }
    }
    bf16x8 af[4], bf[4];
    #pragma unroll
    for (int a = 0; a < 4; ++a)
      af[a] = *(const bf16x8*)(As + c * 4096 + (wr + 16 * a + c15) * 32 + q * 8);
    #pragma unroll
    for (int b = 0; b < 4; ++b)
      bf[b] = *(const bf16x8*)(Bs + cur * 4096 + (wc + 16 * b + c15) * 32 + q * 8);
    #pragma unroll
    for (int a = 0; a < 4; ++a)
      #pragma unroll
      for (int b = 0; b < 4; ++b)
        acc[a][b] = __builtin_amdgcn_mfma_f32_16x16x32_bf16(af[a], bf[b], acc[a][b], 0, 0, 0);
    if (more) {
      #pragma unroll
      for (int u = 0; u < 2; ++u) {
        const int f = tid + 256 * u;
        const int n = f >> 2, j = f & 3;
        *(uint4*)(Bs + (cur ^ 1) * 4096 + n * 32 + j * 8) = st[u];
      }
    }
    __syncthreads();
  }

  // ---- epilogue: activation + u16 stores
  const int colb = wc + c15;
  #pragma unroll
  for (int a = 0; a < 4; ++a) {
    #pragma unroll
    for (int r = 0; r < 4; ++r) {
      const int row = p0 + wr + 16 * a + 4 * q + r;
      u16* yp = outp + (long)row * DVN + colb;
      #pragma unroll
      for (int b = 0; b < 4; ++b) {
        const float v = sel ? tanh_fast(acc[a][b][r]) : sigmoid_fast(acc[a][b][r]);
        yp[16 * b] = f2bf(v);
      }
    }
  }
}

// ============================================================
// kSum: MFMA GEMM. summary = tanh(sin @ W_sum + b). K=256 (8 chunks).
// grid (BSN/128, 2: col half). LDS: A 64KB + B 16KB = 80KB.
// ============================================================
__global__ __launch_bounds__(256) void kSum(
    const u16* __restrict__ X, const u16* __restrict__ WsumT,
    const float* __restrict__ bias, u16* __restrict__ Y)
{
  __shared__ __align__(16) u16 As[8 * 128 * 32];   // 64 KB
  __shared__ __align__(16) u16 Bs[2 * 128 * 32];   // 16 KB
  const int tid = threadIdx.x;
  const int p0  = blockIdx.x * 128;
  const int j0  = blockIdx.y * 128;

  { // stage A (bf16 copy, chunked) — FULL K coverage: 4096 uint4
    #pragma unroll
    for (int u = 0; u < 16; ++u) {
      const int f = tid + 256 * u;           // 0..4095
      const int r = f >> 5, j = f & 31;      // r: row 0..127, j: k-octet 0..31
      const uint4 raw = *(const uint4*)(X + (long)(p0 + r) * DSN + j * 8);
      *(uint4*)(As + (j >> 2) * 4096 + r * 32 + (j & 3) * 8) = raw;
    }
  }
  { // stage B chunk 0
    #pragma unroll
    for (int u = 0; u < 2; ++u) {
      const int f = tid + 256 * u;
      const int n = f >> 2, j = f & 3;
      *(uint4*)(Bs + n * 32 + j * 8) = *(const uint4*)(WsumT + (j0 + n) * 256 + j * 8);
    }
  }
  __syncthreads();

  const int lane = tid & 63, wave = tid >> 6;
  const int wr = (wave >> 1) * 64, wc = (wave & 1) * 64;
  const int c15 = lane & 15, q = lane >> 4;

  f32x4 acc[4][4];
  #pragma unroll
  for (int b = 0; b < 4; ++b) {
    const float bv = bias[j0 + wc + 16 * b + c15];
    #pragma unroll
    for (int a = 0; a < 4; ++a) acc[a][b] = (f32x4){bv, bv, bv, bv};
  }

  for (int c = 0; c < 8; ++c) {
    const int cur = c & 1;
    uint4 st[2];
    const bool more = (c + 1 < 8);
    if (more) {
      #pragma unroll
      for (int u = 0; u < 2; ++u) {
        const int f = tid + 256 * u;
        const int n = f >> 2, j = f & 3;
        st[u] = *(const uint4*)(WsumT + (j0 + n) * 256 + (c + 1) * 32 + j * 8);
      }
    }
    bf16x8 af[4], bf[4];
    #pragma unroll
    for (int a = 0; a < 4; ++a)
      af[a] = *(const bf16x8*)(As + c * 4096 + (wr + 16 * a + c15) * 32 + q * 8);
    #pragma unroll
    for (int b = 0; b < 4; ++b)
      bf[b] = *(const bf16x8*)(Bs + cur * 4096 + (wc + 16 * b + c15) * 32 + q * 8);
    #pragma unroll
    for (int a = 0; a < 4; ++a)
      #pragma unroll
      for (int b = 0; b < 4; ++b)
        acc[a][b] = __builtin_amdgcn_mfma_f32_16x16x32_bf16(af[a], bf[b], acc[a][b], 0, 0, 0);
    if (more) {
      #pragma unroll
      for (int u = 0; u < 2; ++u) {
        const int f = tid + 256 * u;
        const int n = f >> 2, j = f & 3;
        *(uint4*)(Bs + (cur ^ 1) * 4096 + n * 32 + j * 8) = st[u];
      }
    }
    __syncthreads();
  }

  const int colb = j0 + wc + c15;
  #pragma unroll
  for (int a = 0; a < 4; ++a) {
    #pragma unroll
    for (int r = 0; r < 4; ++r) {
      const int row = p0 + wr + 16 * a + 4 * q + r;
      u16* yp = Y + (long)row * DSN + colb;
      #pragma unroll
      for (int b = 0; b < 4; ++b)
        yp[16 * b] = f2bf(tanh_fast(acc[a][b][r]));
    }
  }
}

// ============================================================
// kAb: MFMA GEMM + fused W_ab2 dot.
// ============================================================
__global__ __launch_bounds__(256) void kAb(
    const u16* __restrict__ X, const u16* __restrict__ Wab1T,
    const float* __restrict__ bias, const float* __restrict__ Wab2,
    float* __restrict__ part)
{
  __shared__ __align__(16) u16 As[8 * 128 * 32];
  __shared__ __align__(16) u16 Bs[2 * 128 * 32];
  const int tid = threadIdx.x;
  const int p0  = blockIdx.x * 128;
  const int j0  = blockIdx.y * 128;

  { // stage A — FULL K coverage: 4096 uint4
    #pragma unroll
    for (int u = 0; u < 16; ++u) {
      const int f = tid + 256 * u;
      const int r = f >> 5, j = f & 31;
      const uint4 raw = *(const uint4*)(X + (long)(p0 + r) * DSN + j * 8);
      *(uint4*)(As + (j >> 2) * 4096 + r * 32 + (j & 3) * 8) = raw;
    }
  }
  {
    #pragma unroll
    for (int u = 0; u < 2; ++u) {
      const int f = tid + 256 * u;
      const int n = f >> 2, j = f & 3;
      *(uint4*)(Bs + n * 32 + j * 8) = *(const uint4*)(Wab1T + (j0 + n) * 256 + j * 8);
    }
  }
  __syncthreads();

  const int lane = tid & 63, wave = tid >> 6;
  const int wr = (wave >> 1) * 64, wc = (wave & 1) * 64;
  const int c15 = lane & 15, q = lane >> 4;

  f32x4 acc[4][4];
  float w2v[4];
  #pragma unroll
  for (int b = 0; b < 4; ++b) {
    const int col = j0 + wc + 16 * b + c15;
    const float bv = bias[col];
    w2v[b] = Wab2[col];
    #pragma unroll
    for (int a = 0; a < 4; ++a) acc[a][b] = (f32x4){bv, bv, bv, bv};
  }

  for (int c = 0; c < 8; ++c) {
    const int cur = c & 1;
    uint4 st[2];
    const bool more = (c + 1 < 8);
    if (more) {
      #pragma unroll
      for (int u = 0; u < 2; ++u) {
        const int f = tid + 256 * u;
        const int n = f >> 2, j = f & 3;
        st[u] = *(const uint4*)(Wab1T + (j0 + n) * 256 + (c + 1) * 32 + j * 8);
      }
    }
    bf16x8 af[4], bf[4];
    #pragma unroll
    for (int a = 0; a < 4; ++a)
      af[a] = *(const bf16x8*)(As + c * 4096 + (wr + 16 * a + c15) * 32 + q * 8);
    #pragma unroll
    for (int b = 0; b < 4; ++b)
      bf[b] = *(const bf16x8*)(Bs + cur * 4096 + (wc + 16 * b + c15) * 32 + q * 8);
    #pragma unroll
    for (int a = 0; a < 4; ++a)
      #pragma unroll
      for (int b = 0; b < 4; ++b)
        acc[a][b] = __builtin_amdgcn_mfma_f32_16x16x32_bf16(af[a], bf[b], acc[a][b], 0, 0, 0);
    if (more) {
      #pragma unroll
      for (int u = 0; u < 2; ++u) {
        const int f = tid + 256 * u;
        const int n = f >> 2, j = f & 3;
        *(uint4*)(Bs + (cur ^ 1) * 4096 + n * 32 + j * 8) = st[u];
      }
    }
    __syncthreads();   // final barrier also fences Bs reuse below
  }

  // ---- epilogue: tanh, dot with W_ab2, reduce 16 col-lanes, pair waves
  float sv[4][4];
  #pragma unroll
  for (int a = 0; a < 4; ++a) {
    #pragma unroll
    for (int r = 0; r < 4; ++r) {
      float s = 0.f;
      #pragma unroll
      for (int b = 0; b < 4; ++b)
        s = fmaf(tanh_fast(acc[a][b][r]), w2v[b], s);
      s += __shfl_xor(s, 1, 64);
      s += __shfl_xor(s, 2, 64);
      s += __shfl_xor(s, 4, 64);
      s += __shfl_xor(s, 8, 64);
      sv[a][r] = s;
    }
  }
  float* red = (float*)Bs;   // 128 f32, reuse (fenced by loop's last barrier)
  if ((wave & 1) && c15 == 0) {
    #pragma unroll
    for (int a = 0; a < 4; ++a)
      #pragma unroll
      for (int r = 0; r < 4; ++r)
        red[wr + 16 * a + 4 * q + r] = sv[a][r];
  }
  __syncthreads();
  if (!(wave & 1) && c15 == 0) {
    #pragma unroll
    for (int a = 0; a < 4; ++a)
      #pragma unroll
      for (int r = 0; r < 4; ++r) {
        const int rr = wr + 16 * a + 4 * q + r;
        part[(long)blockIdx.y * BSN + p0 + rr] = sv[a][r] + red[rr];
      }
  }
}

// ============================================================
// kQe (MFMA): one GEMM qe[128x128] @ BqT^T[128x160] per block.
// cols 0..31 = attention scores -> softmax -> w_all
// cols 32..159 = df hidden -> tanh -> dot W_df2 -> diff
// qe -> sinb copy fused into A staging.
// ============================================================
__global__ __launch_bounds__(256) void kQe(
    const int* __restrict__ q_data, const float* __restrict__ q_table,
    const u16* __restrict__ BqT,
    const float* __restrict__ bdf1, const float* __restrict__ Wdf2,
    const float* __restrict__ bdf2,
    float* __restrict__ w_all, float* __restrict__ diff,
    u16* __restrict__ sin_buf)
{
  __shared__ __align__(16) u16 As[4 * 128 * 32];   // 32 KB [chunk][row][k']
  __shared__ __align__(16) u16 Bs[4 * 160 * 32];   // 40 KB [chunk][n][k']
  const int tid = threadIdx.x;
  const int p0  = blockIdx.x * 128;

  // ---- stage A: gather qe rows (f32->bf16), fused sinb store
  {
    const int r = tid >> 1, h = tid & 1;
    const long base = (long)q_data[p0 + r] * DKN + h * 64;
    #pragma unroll
    for (int g = 0; g < 8; ++g) {
      const int k0 = h * 64 + g * 8;
      const float4 fa = *(const float4*)(q_table + base + g * 8);
      const float4 fb = *(const float4*)(q_table + base + g * 8 + 4);
      uint4 pk;
      pk.x = pack2(fa.x, fa.y); pk.y = pack2(fa.z, fa.w);
      pk.z = pack2(fb.x, fb.y); pk.w = pack2(fb.z, fb.w);
      *(uint4*)(As + (k0 >> 5) * 4096 + r * 32 + (k0 & 31)) = pk;
      *(uint4*)(sin_buf + (long)(p0 + r) * DSN + DKN + k0) = pk;
    }
  }
  // ---- stage B: 160 rows x 128 k = 2560 uint4 (10/thread)
  {
    #pragma unroll
    for (int u = 0; u < 10; ++u) {
      const int f = tid + 256 * u;           // 0..2559
      const int n = f >> 4, jj = f & 15;
      *(uint4*)(Bs + (jj >> 2) * 5120 + n * 32 + (jj & 3) * 8) =
          *(const uint4*)(BqT + n * 128 + jj * 8);
    }
  }
  __syncthreads();

  const int lane = tid & 63, wave = tid >> 6;
  const int wr = (wave >> 1) * 64, wc = (wave & 1) * 80;
  const int c15 = lane & 15, q = lane >> 4;

  f32x4 acc[4][5];
  float w2v[5];
  #pragma unroll
  for (int b = 0; b < 5; ++b) {
    const int col = wc + 16 * b + c15;
    const float bv = (col < 32) ? 0.f : bdf1[col - 32];
    w2v[b] = (col < 32) ? 0.f : Wdf2[col - 32];
    #pragma unroll
    for (int a = 0; a < 4; ++a) acc[a][b] = (f32x4){bv, bv, bv, bv};
  }

  #pragma unroll
  for (int c = 0; c < 4; ++c) {
    bf16x8 af[4], bf[5];
    #pragma unroll
    for (int a = 0; a < 4; ++a)
      af[a] = *(const bf16x8*)(As + c * 4096 + (wr + 16 * a + c15) * 32 + q * 8);
    #pragma unroll
    for (int b = 0; b < 5; ++b)
      bf[b] = *(const bf16x8*)(Bs + c * 5120 + (wc + 16 * b + c15) * 32 + q * 8);
    #pragma unroll
    for (int a = 0; a < 4; ++a)
      #pragma unroll
      for (int b = 0; b < 5; ++b)
        acc[a][b] = __builtin_amdgcn_mfma_f32_16x16x32_bf16(af[a], bf[b], acc[a][b], 0, 0, 0);
  }

  // ---- softmax over cols 0..31 (waves with wc==0 only: b=0,1)
  if (wc == 0) {
    #pragma unroll
    for (int a = 0; a < 4; ++a) {
      #pragma unroll
      for (int r = 0; r < 4; ++r) {
        float s0 = acc[a][0][r], s1 = acc[a][1][r];
        float mx = fmaxf(s0, s1);
        mx = fmaxf(mx, __shfl_xor(mx, 1, 64));
        mx = fmaxf(mx, __shfl_xor(mx, 2, 64));
        mx = fmaxf(mx, __shfl_xor(mx, 4, 64));
        mx = fmaxf(mx, __shfl_xor(mx, 8, 64));
        const float e0 = __expf(s0 - mx), e1 = __expf(s1 - mx);
        float sm = e0 + e1;
        sm += __shfl_xor(sm, 1, 64);
        sm += __shfl_xor(sm, 2, 64);
        sm += __shfl_xor(sm, 4, 64);
        sm += __shfl_xor(sm, 8, 64);
        const float inv = 1.f / sm;
        const int row = p0 + wr + 16 * a + 4 * q + r;
        w_all[(long)row * MEMN + c15]      = e0 * inv;
        w_all[(long)row * MEMN + 16 + c15] = e1 * inv;
      }
    }
  }

  // ---- diff partials: tanh + W_df2 dot (w2v==0 masks attention cols)
  float sv[4][4];
  #pragma unroll
  for (int a = 0; a < 4; ++a) {
    #pragma unroll
    for (int r = 0; r < 4; ++r) {
      float s = 0.f;
      #pragma unroll
      for (int b = 0; b < 5; ++b)
        s = fmaf(tanh_fast(acc[a][b][r]), w2v[b], s);
      s += __shfl_xor(s, 1, 64);
      s += __shfl_xor(s, 2, 64);
      s += __shfl_xor(s, 4, 64);
      s += __shfl_xor(s, 8, 64);
      sv[a][r] = s;
    }
  }
  __syncthreads();               // all MFMA LDS reads done; reuse As
  float* red = (float*)As;       // 128 f32
  if ((wave & 1) && c15 == 0) {  // wc==80 waves
    #pragma unroll
    for (int a = 0; a < 4; ++a)
      #pragma unroll
      for (int r = 0; r < 4; ++r)
        red[wr + 16 * a + 4 * q + r] = sv[a][r];
  }
  __syncthreads();
  if (!(wave & 1) && c15 == 0) {
    const float bd = bdf2[0];
    #pragma unroll
    for (int a = 0; a < 4; ++a)
      #pragma unroll
      for (int r = 0; r < 4; ++r) {
        const int rr = wr + 16 * a + 4 * q + r;
        diff[p0 + rr] = sv[a][r] + red[rr] + bd;
      }
  }
}

// ============================================================
// kScan v4: 2 threads/col (4 waves -> all 4 SIMDs), async LDS chunk
// staging (unchanged), 2-step register prefetch (triple-rotated sets,
// 32-step full unroll so s%3 constant-folds).
// thread: c = tid>>1 (col), h = tid&1 (rows h*16..h*16+15), Mv[16].
// pair-reduce via one shfl_xor(1). Junk tail reads land in LDS pad.
// ============================================================
#define CHUNK_BYTES 20480

#define KSTAGE(K, BUF)                                                        \
  {                                                                           \
    const char* wsrc = (const char*)(w_all + (pbase + (long)(K) * 32) * MEMN);\
    const char* esrc = (const char*)(eras + (pbase + (long)(K) * 32) * DVN);  \
    const char* asrc = (const char*)(addb + (pbase + (long)(K) * 32) * DVN);  \
    char* dst = lds + (BUF) * CHUNK_BYTES;                                    \
    _Pragma("unroll")                                                         \
    for (int r = 0; r < 5; ++r) {                                             \
      const int o = (tid + r * 256) * 16;                                     \
      const char* src = (o < 4096) ? (wsrc + o)                               \
                      : (o < 12288) ? (esrc + (o - 4096))                     \
                                    : (asrc + (o - 12288));                   \
      GLOAD_LDS16(src, dst + o);                                              \
    }                                                                         \
  }

__global__ __launch_bounds__(256) void kScan(
    const float* __restrict__ w_all, const u16* __restrict__ eras,
    const u16* __restrict__ addb, const float* __restrict__ init_mem,
    u16* __restrict__ sin_buf)
{
  __shared__ __align__(16) char lds[2 * CHUNK_BYTES + 512];   // pad for junk tail reads
  const int tid = threadIdx.x;
  const int c = tid >> 1;        // column 0..127
  const int h = tid & 1;         // row half: rows h*16 .. h*16+15
  const long pbase = (long)blockIdx.x * S_N;

  float Mv[16];
  #pragma unroll
  for (int m = 0; m < 16; ++m) Mv[m] = init_mem[(h * 16 + m) * DVN + c];

  u16* sp = sin_buf + pbase * DSN + c;

  KSTAGE(0, 0)
  for (int k = 0; k < 16; ++k) {
    __syncthreads();                       // chunk k staged
    if (k + 1 < 16) KSTAGE(k + 1, (k + 1) & 1)

    const char*  wb  = lds + (k & 1) * CHUNK_BYTES;
    const f32x4* wl4 = (const f32x4*)wb;            // [32 steps][8 f32x4]; thread uses h*4..h*4+3
    const u16*   el  = (const u16*)(wb + 4096);     // [32][128]
    const u16*   al  = (const u16*)(wb + 12288);    // [32][128]
    const int lb = k * 32;

    f32x4 Wr[3][4];
    u16 er[3], ar[3];
    #pragma unroll
    for (int i = 0; i < 4; ++i) Wr[0][i] = wl4[h * 4 + i];
    er[0] = el[c]; ar[0] = al[c];
    #pragma unroll
    for (int i = 0; i < 4; ++i) Wr[1][i] = wl4[8 + h * 4 + i];
    er[1] = el[128 + c]; ar[1] = al[128 + c];

    #pragma unroll
    for (int s = 0; s < 32; ++s) {
      const int cur = s % 3, nx2 = (s + 2) % 3;
      // prefetch step s+2 (s>=30: junk reads within chunk/pad, unused)
      #pragma unroll
      for (int i = 0; i < 4; ++i) Wr[nx2][i] = wl4[(s + 2) * 8 + h * 4 + i];
      er[nx2] = el[(s + 2) * 128 + c];
      ar[nx2] = al[(s + 2) * 128 + c];
      // compute step s
      {
        float ac0 = 0.f, ac1 = 0.f, ac2 = 0.f, ac3 = 0.f;
        #pragma unroll
        for (int i = 0; i < 4; ++i) {
          ac0 = fmaf(Wr[cur][i][0], Mv[4 * i + 0], ac0);
          ac1 = fmaf(Wr[cur][i][1], Mv[4 * i + 1], ac1);
          ac2 = fmaf(Wr[cur][i][2], Mv[4 * i + 2], ac2);
          ac3 = fmaf(Wr[cur][i][3], Mv[4 * i + 3], ac3);
        }
        float pr = (ac0 + ac1) + (ac2 + ac3);
        pr += __shfl_xor(pr, 1, 64);          // combine h=0 and h=1 halves
        if (h == 0) sp[(long)(lb + s) * DSN] = f2bf(pr);
        const float ec = bf2f(er[cur]);
        const float an = -bf2f(ar[cur]);
        #pragma unroll
        for (int i = 0; i < 4; ++i) {
          #pragma unroll
          for (int j = 0; j < 4; ++j) {
            const float t = fmaf(ec, Mv[4 * i + j], an);
            Mv[4 * i + j] = fmaf(-Wr[cur][i][j], t, Mv[4 * i + j]);
          }
        }
      }
    }
  }
}

// ============================================================
// kOut: combine. grid (BSN/256), block 256. f32 output.
// ============================================================
__global__ __launch_bounds__(256) void kOut(
    const float* __restrict__ part, const float* __restrict__ diff,
    const float* __restrict__ bab2, float* __restrict__ out)
{
  const int p = blockIdx.x * 256 + threadIdx.x;
  const float ab = part[p] + part[BSN + p] + bab2[0];
  const float d  = diff[p];
  const float z  = 3.0f * ab - d;
  out[p]           = sigmoid_fast(z);
  out[BSN + p]     = ab;
  out[2 * BSN + p] = d;
  out[3 * BSN + p] = z;
}

// ============================================================
// launch
// ============================================================
extern "C" void kernel_launch(void* const* d_in, const int* in_sizes, int n_in,
                              void* d_out, int out_size, void* d_ws, size_t ws_size,
                              hipStream_t stream)
{
  const int*   q_data   = (const int*)d_in[0];
  const int*   qa_data  = (const int*)d_in[1];
  const float* q_table  = (const float*)d_in[2];
  const float* qa_table = (const float*)d_in[3];
  const float* key_mem  = (const float*)d_in[4];
  const float* init_mem = (const float*)d_in[5];
  const float* W_erase  = (const float*)d_in[6];
  const float* b_erase  = (const float*)d_in[7];
  const float* W_add    = (const float*)d_in[8];
  const float* b_add    = (const float*)d_in[9];
  const float* W_sum    = (const float*)d_in[10];
  const float* b_sum    = (const float*)d_in[11];
  const float* W_ab1    = (const float*)d_in[12];
  const float* b_ab1    = (const float*)d_in[13];
  const float* W_ab2    = (const float*)d_in[14];
  const float* b_ab2    = (const float*)d_in[15];
  const float* W_df1    = (const float*)d_in[16];
  const float* b_df1    = (const float*)d_in[17];
  const float* W_df2    = (const float*)d_in[18];
  const float* b_df2    = (const float*)d_in[19];

  // workspace layout (bytes); total 152,936,448
  char* ws = (char*)d_ws;
  float* w_all = (float*)(ws + 0);           // [BS][32] f32   16,777,216
  u16*   eras  = (u16*)(ws + 16777216);      // [BS][128] bf16 33,554,432
  u16*   addb  = (u16*)(ws + 50331648);      // [BS][128] bf16 33,554,432
  u16*   sinb  = (u16*)(ws + 83886080);      // [BS][256] bf16 67,108,864
  float* diffb = (float*)(ws + 150994944);   // [BS] f32          524,288
  float* part  = (float*)(ws + 151519232);   // [2][BS] f32     1,048,576
  u16*   WerT  = (u16*)(ws + 152567808);     // 32,768
  u16*   WaddT = (u16*)(ws + 152600576);     // 32,768
  u16*   WsumT = (u16*)(ws + 152633344);     // 131,072
  u16*   Wab1T = (u16*)(ws + 152764416);     // 131,072
  u16*   BqT   = (u16*)(ws + 152895488);     // 160x128 bf16 = 40,960
  u16*   summ  = eras;                       // summary reuses eras+addb

  kPrep<<<dim3(720), 256, 0, stream>>>(W_sum, W_ab1, W_erase, W_add, key_mem, W_df1,
                                       WsumT, Wab1T, WerT, WaddT, BqT);
  kErAdd<<<dim3(BSN / 128, 2), 256, 0, stream>>>(qa_data, qa_table, WerT, WaddT,
                                                 b_erase, b_add, eras, addb);
  kQe<<<dim3(BSN / 128), 256, 0, stream>>>(q_data, q_table, BqT, b_df1, W_df2, b_df2,
                                           w_all, diffb, sinb);
  kScan<<<dim3(B_N), 256, 0, stream>>>(w_all, eras, addb, init_mem, sinb);
  kSum<<<dim3(BSN / 128, 2), 256, 0, stream>>>(sinb, WsumT, b_sum, summ);
  kAb<<<dim3(BSN / 128, 2), 256, 0, stream>>>(summ, Wab1T, b_ab1, W_ab2, part);
  kOut<<<dim3(BSN / 256), 256, 0, stream>>>(part, diffb, b_ab2, (float*)d_out);
}

// Round 11
// 378.001 us; speedup vs baseline: 1.1313x; 1.0031x over previous
//
#include <hip/hip_runtime.h>
#include <hip/hip_bf16.h>

typedef unsigned short u16;
typedef unsigned int   u32;

#define B_N   256
#define S_N   512
#define BSN   (B_N * S_N)      // 131072 positions
#define MEMN  32
#define DKN   128
#define DVN   128
#define DSN   256

typedef __attribute__((ext_vector_type(8))) short bf16x8;
typedef __attribute__((ext_vector_type(4))) float f32x4;

// ---------- helpers ----------
__device__ __forceinline__ float bf2f(u16 u) {
  union { u32 i; float f; } v; v.i = ((u32)u) << 16; return v.f;
}
__device__ __forceinline__ u16 f2bf(float f) {
  union { float f; u32 i; } v; v.f = f;
  u32 x = v.i;
  x += 0x7fffu + ((x >> 16) & 1u);   // RNE
  return (u16)(x >> 16);
}
__device__ __forceinline__ u32 pack2(float a, float b) {
  return (u32)f2bf(a) | ((u32)f2bf(b) << 16);
}
__device__ __forceinline__ float sigmoid_fast(float x) { return 1.f / (1.f + __expf(-x)); }
__device__ __forceinline__ float tanh_fast(float x)    { return 1.f - 2.f / (__expf(2.f * x) + 1.f); }

#define GLOAD_LDS16(g, l)                                         \
  __builtin_amdgcn_global_load_lds(                               \
      (const __attribute__((address_space(1))) void*)(g),         \
      (__attribute__((address_space(3))) void*)(l), 16, 0, 0)

// ============================================================
// kPrep: transpose + bf16-convert weights; build concatenated BqT:
// BqT[n][k], n<32: key_mem[n][k]; n>=32: W_df1[k][n-32].   184320 elems.
// ============================================================
__global__ __launch_bounds__(256) void kPrep(
    const float* __restrict__ W_sum, const float* __restrict__ W_ab1,
    const float* __restrict__ W_er,  const float* __restrict__ W_ad,
    const float* __restrict__ key_mem, const float* __restrict__ W_df1,
    u16* __restrict__ WsumT, u16* __restrict__ Wab1T,
    u16* __restrict__ WerT,  u16* __restrict__ WaddT,
    u16* __restrict__ BqT)
{
  int e = blockIdx.x * 256 + threadIdx.x;
  if (e < 65536) {
    const int n = e >> 8, k = e & 255;
    WsumT[e] = f2bf(W_sum[k * 256 + n]);
  } else if (e < 131072) {
    e -= 65536;
    const int n = e >> 8, k = e & 255;
    Wab1T[e] = f2bf(W_ab1[k * 256 + n]);
  } else if (e < 147456) {
    e -= 131072;
    const int n = e >> 7, k = e & 127;
    WerT[e] = f2bf(W_er[k * 128 + n]);
  } else if (e < 163840) {
    e -= 147456;
    const int n = e >> 7, k = e & 127;
    WaddT[e] = f2bf(W_ad[k * 128 + n]);
  } else if (e < 184320) {
    e -= 163840;
    const int n = e >> 7, k = e & 127;
    BqT[e] = f2bf(n < 32 ? key_mem[n * 128 + k] : W_df1[k * 128 + (n - 32)]);
  }
}

// ============================================================
// kErAdd: MFMA GEMM. out = act(qae @ W + b), W pre-transposed bf16.
// grid (BSN/128, 2), block 256 (4 waves, 64x64 tiles). y: 0=erase, 1=add.
// ============================================================
__global__ __launch_bounds__(256) void kErAdd(
    const int* __restrict__ qa_data, const float* __restrict__ qa_table,
    const u16* __restrict__ WerT, const u16* __restrict__ WaddT,
    const float* __restrict__ b_er, const float* __restrict__ b_ad,
    u16* __restrict__ eras, u16* __restrict__ addb)
{
  __shared__ __align__(16) u16 As[4 * 128 * 32];   // [chunk][m][k'] 32 KB
  __shared__ __align__(16) u16 Bs[2 * 128 * 32];   // dbuf [n][k'] 16 KB
  const int tid = threadIdx.x;
  const int p0  = blockIdx.x * 128;
  const int sel = blockIdx.y;
  const u16*   Wt = sel ? WaddT : WerT;
  const float* bb = sel ? b_ad  : b_er;
  u16*       outp = sel ? addb  : eras;

  // ---- stage A: gather 128 rows of qa_table (f32 -> bf16), chunked layout
  {
    const int r = tid >> 1, h = tid & 1;
    const long base = (long)qa_data[p0 + r] * DVN + h * 64;
    #pragma unroll
    for (int g = 0; g < 8; ++g) {
      const int k0 = h * 64 + g * 8;
      const float4 fa = *(const float4*)(qa_table + base + g * 8);
      const float4 fb = *(const float4*)(qa_table + base + g * 8 + 4);
      uint4 pk;
      pk.x = pack2(fa.x, fa.y); pk.y = pack2(fa.z, fa.w);
      pk.z = pack2(fb.x, fb.y); pk.w = pack2(fb.z, fb.w);
      *(uint4*)(As + (k0 >> 5) * 4096 + r * 32 + (k0 & 31)) = pk;
    }
  }
  // ---- stage B chunk 0
  {
    #pragma unroll
    for (int u = 0; u < 2; ++u) {
      const int f = tid + 256 * u;           // 0..511
      const int n = f >> 2, j = f & 3;
      *(uint4*)(Bs + n * 32 + j * 8) = *(const uint4*)(Wt + n * 128 + j * 8);
    }
  }
  __syncthreads();

  const int lane = tid & 63, wave = tid >> 6;
  const int wr = (wave >> 1) * 64, wc = (wave & 1) * 64;
  const int c15 = lane & 15, q = lane >> 4;

  f32x4 acc[4][4];
  #pragma unroll
  for (int b = 0; b < 4; ++b) {
    const float bv = bb[wc + 16 * b + c15];
    #pragma unroll
    for (int a = 0; a < 4; ++a) acc[a][b] = (f32x4){bv, bv, bv, bv};
  }

  for (int c = 0; c < 4; ++c) {
    const int cur = c & 1;
    uint4 st[2];
    const bool more = (c + 1 < 4);
    if (more) {
      #pragma unroll
      for (int u = 0; u < 2; ++u) {
        const int f = tid + 256 * u;
        const int n = f >> 2, j = f & 3;
        st[u] = *(const uint4*)(Wt + n * 128 + (c + 1) * 32 + j * 8);
      }
    }
    bf16x8 af[4], bf[4];
    #pragma unroll
    for (int a = 0; a < 4; ++a)
      af[a] = *(const bf16x8*)(As + c * 4096 + (wr + 16 * a + c15) * 32 + q * 8);
    #pragma unroll
    for (int b = 0; b < 4; ++b)
      bf[b] = *(const bf16x8*)(Bs + cur * 4096 + (wc + 16 * b + c15) * 32 + q * 8);
    #pragma unroll
    for (int a = 0; a < 4; ++a)
      #pragma unroll
      for (int b = 0; b < 4; ++b)
        acc[a][b] = __builtin_amdgcn_mfma_f32_16x16x32_bf16(af[a], bf[b], acc[a][b], 0, 0, 0);
    if (more) {
      #pragma unroll
      for (int u = 0; u < 2; ++u) {
        const int f = tid + 256 * u;
        const int n = f >> 2, j = f & 3;
        *(uint4*)(Bs + (cur ^ 1) * 4096 + n * 32 + j * 8) = st[u];
      }
    }
    __syncthreads();
  }

  // ---- epilogue: activation + u16 stores
  const int colb = wc + c15;
  #pragma unroll
  for (int a = 0; a < 4; ++a) {
    #pragma unroll
    for (int r = 0; r < 4; ++r) {
      const int row = p0 + wr + 16 * a + 4 * q + r;
      u16* yp = outp + (long)row * DVN + colb;
      #pragma unroll
      for (int b = 0; b < 4; ++b) {
        const float v = sel ? tanh_fast(acc[a][b][r]) : sigmoid_fast(acc[a][b][r]);
        yp[16 * b] = f2bf(v);
      }
    }
  }
}

// ============================================================
// kSum: MFMA GEMM. summary = tanh(sin @ W_sum + b). K=256 (8 chunks).
// grid (BSN/128, 2: col half). LDS: A 64KB + B 16KB = 80KB.
// ============================================================
__global__ __launch_bounds__(256) void kSum(
    const u16* __restrict__ X, const u16* __restrict__ WsumT,
    const float* __restrict__ bias, u16* __restrict__ Y)
{
  __shared__ __align__(16) u16 As[8 * 128 * 32];   // 64 KB
  __shared__ __align__(16) u16 Bs[2 * 128 * 32];   // 16 KB
  const int tid = threadIdx.x;
  const int p0  = blockIdx.x * 128;
  const int j0  = blockIdx.y * 128;

  { // stage A (bf16 copy, chunked) — FULL K coverage: 4096 uint4
    #pragma unroll
    for (int u = 0; u < 16; ++u) {
      const int f = tid + 256 * u;           // 0..4095
      const int r = f >> 5, j = f & 31;      // r: row 0..127, j: k-octet 0..31
      const uint4 raw = *(const uint4*)(X + (long)(p0 + r) * DSN + j * 8);
      *(uint4*)(As + (j >> 2) * 4096 + r * 32 + (j & 3) * 8) = raw;
    }
  }
  { // stage B chunk 0
    #pragma unroll
    for (int u = 0; u < 2; ++u) {
      const int f = tid + 256 * u;
      const int n = f >> 2, j = f & 3;
      *(uint4*)(Bs + n * 32 + j * 8) = *(const uint4*)(WsumT + (j0 + n) * 256 + j * 8);
    }
  }
  __syncthreads();

  const int lane = tid & 63, wave = tid >> 6;
  const int wr = (wave >> 1) * 64, wc = (wave & 1) * 64;
  const int c15 = lane & 15, q = lane >> 4;

  f32x4 acc[4][4];
  #pragma unroll
  for (int b = 0; b < 4; ++b) {
    const float bv = bias[j0 + wc + 16 * b + c15];
    #pragma unroll
    for (int a = 0; a < 4; ++a) acc[a][b] = (f32x4){bv, bv, bv, bv};
  }

  for (int c = 0; c < 8; ++c) {
    const int cur = c & 1;
    uint4 st[2];
    const bool more = (c + 1 < 8);
    if (more) {
      #pragma unroll
      for (int u = 0; u < 2; ++u) {
        const int f = tid + 256 * u;
        const int n = f >> 2, j = f & 3;
        st[u] = *(const uint4*)(WsumT + (j0 + n) * 256 + (c + 1) * 32 + j * 8);
      }
    }
    bf16x8 af[4], bf[4];
    #pragma unroll
    for (int a = 0; a < 4; ++a)
      af[a] = *(const bf16x8*)(As + c * 4096 + (wr + 16 * a + c15) * 32 + q * 8);
    #pragma unroll
    for (int b = 0; b < 4; ++b)
      bf[b] = *(const bf16x8*)(Bs + cur * 4096 + (wc + 16 * b + c15) * 32 + q * 8);
    #pragma unroll
    for (int a = 0; a < 4; ++a)
      #pragma unroll
      for (int b = 0; b < 4; ++b)
        acc[a][b] = __builtin_amdgcn_mfma_f32_16x16x32_bf16(af[a], bf[b], acc[a][b], 0, 0, 0);
    if (more) {
      #pragma unroll
      for (int u = 0; u < 2; ++u) {
        const int f = tid + 256 * u;
        const int n = f >> 2, j = f & 3;
        *(uint4*)(Bs + (cur ^ 1) * 4096 + n * 32 + j * 8) = st[u];
      }
    }
    __syncthreads();
  }

  const int colb = j0 + wc + c15;
  #pragma unroll
  for (int a = 0; a < 4; ++a) {
    #pragma unroll
    for (int r = 0; r < 4; ++r) {
      const int row = p0 + wr + 16 * a + 4 * q + r;
      u16* yp = Y + (long)row * DSN + colb;
      #pragma unroll
      for (int b = 0; b < 4; ++b)
        yp[16 * b] = f2bf(tanh_fast(acc[a][b][r]));
    }
  }
}

// ============================================================
// kAb: MFMA GEMM + fused W_ab2 dot.
// ============================================================
__global__ __launch_bounds__(256) void kAb(
    const u16* __restrict__ X, const u16* __restrict__ Wab1T,
    const float* __restrict__ bias, const float* __restrict__ Wab2,
    float* __restrict__ part)
{
  __shared__ __align__(16) u16 As[8 * 128 * 32];
  __shared__ __align__(16) u16 Bs[2 * 128 * 32];
  const int tid = threadIdx.x;
  const int p0  = blockIdx.x * 128;
  const int j0  = blockIdx.y * 128;

  { // stage A — FULL K coverage: 4096 uint4
    #pragma unroll
    for (int u = 0; u < 16; ++u) {
      const int f = tid + 256 * u;
      const int r = f >> 5, j = f & 31;
      const uint4 raw = *(const uint4*)(X + (long)(p0 + r) * DSN + j * 8);
      *(uint4*)(As + (j >> 2) * 4096 + r * 32 + (j & 3) * 8) = raw;
    }
  }
  {
    #pragma unroll
    for (int u = 0; u < 2; ++u) {
      const int f = tid + 256 * u;
      const int n = f >> 2, j = f & 3;
      *(uint4*)(Bs + n * 32 + j * 8) = *(const uint4*)(Wab1T + (j0 + n) * 256 + j * 8);
    }
  }
  __syncthreads();

  const int lane = tid & 63, wave = tid >> 6;
  const int wr = (wave >> 1) * 64, wc = (wave & 1) * 64;
  const int c15 = lane & 15, q = lane >> 4;

  f32x4 acc[4][4];
  float w2v[4];
  #pragma unroll
  for (int b = 0; b < 4; ++b) {
    const int col = j0 + wc + 16 * b + c15;
    const float bv = bias[col];
    w2v[b] = Wab2[col];
    #pragma unroll
    for (int a = 0; a < 4; ++a) acc[a][b] = (f32x4){bv, bv, bv, bv};
  }

  for (int c = 0; c < 8; ++c) {
    const int cur = c & 1;
    uint4 st[2];
    const bool more = (c + 1 < 8);
    if (more) {
      #pragma unroll
      for (int u = 0; u < 2; ++u) {
        const int f = tid + 256 * u;
        const int n = f >> 2, j = f & 3;
        st[u] = *(const uint4*)(Wab1T + (j0 + n) * 256 + (c + 1) * 32 + j * 8);
      }
    }
    bf16x8 af[4], bf[4];
    #pragma unroll
    for (int a = 0; a < 4; ++a)
      af[a] = *(const bf16x8*)(As + c * 4096 + (wr + 16 * a + c15) * 32 + q * 8);
    #pragma unroll
    for (int b = 0; b < 4; ++b)
      bf[b] = *(const bf16x8*)(Bs + cur * 4096 + (wc + 16 * b + c15) * 32 + q * 8);
    #pragma unroll
    for (int a = 0; a < 4; ++a)
      #pragma unroll
      for (int b = 0; b < 4; ++b)
        acc[a][b] = __builtin_amdgcn_mfma_f32_16x16x32_bf16(af[a], bf[b], acc[a][b], 0, 0, 0);
    if (more) {
      #pragma unroll
      for (int u = 0; u < 2; ++u) {
        const int f = tid + 256 * u;
        const int n = f >> 2, j = f & 3;
        *(uint4*)(Bs + (cur ^ 1) * 4096 + n * 32 + j * 8) = st[u];
      }
    }
    __syncthreads();   // final barrier also fences Bs reuse below
  }

  // ---- epilogue: tanh, dot with W_ab2, reduce 16 col-lanes, pair waves
  float sv[4][4];
  #pragma unroll
  for (int a = 0; a < 4; ++a) {
    #pragma unroll
    for (int r = 0; r < 4; ++r) {
      float s = 0.f;
      #pragma unroll
      for (int b = 0; b < 4; ++b)
        s = fmaf(tanh_fast(acc[a][b][r]), w2v[b], s);
      s += __shfl_xor(s, 1, 64);
      s += __shfl_xor(s, 2, 64);
      s += __shfl_xor(s, 4, 64);
      s += __shfl_xor(s, 8, 64);
      sv[a][r] = s;
    }
  }
  float* red = (float*)Bs;   // 128 f32, reuse (fenced by loop's last barrier)
  if ((wave & 1) && c15 == 0) {
    #pragma unroll
    for (int a = 0; a < 4; ++a)
      #pragma unroll
      for (int r = 0; r < 4; ++r)
        red[wr + 16 * a + 4 * q + r] = sv[a][r];
  }
  __syncthreads();
  if (!(wave & 1) && c15 == 0) {
    #pragma unroll
    for (int a = 0; a < 4; ++a)
      #pragma unroll
      for (int r = 0; r < 4; ++r) {
        const int rr = wr + 16 * a + 4 * q + r;
        part[(long)blockIdx.y * BSN + p0 + rr] = sv[a][r] + red[rr];
      }
  }
}

// ============================================================
// kQe (MFMA): one GEMM qe[128x128] @ BqT^T[128x160] per block.
// cols 0..31 = attention scores -> softmax -> w_all
// cols 32..159 = df hidden -> tanh -> dot W_df2 -> diff
// qe -> sinb copy fused into A staging.
// ============================================================
__global__ __launch_bounds__(256) void kQe(
    const int* __restrict__ q_data, const float* __restrict__ q_table,
    const u16* __restrict__ BqT,
    const float* __restrict__ bdf1, const float* __restrict__ Wdf2,
    const float* __restrict__ bdf2,
    float* __restrict__ w_all, float* __restrict__ diff,
    u16* __restrict__ sin_buf)
{
  __shared__ __align__(16) u16 As[4 * 128 * 32];   // 32 KB [chunk][row][k']
  __shared__ __align__(16) u16 Bs[4 * 160 * 32];   // 40 KB [chunk][n][k']
  const int tid = threadIdx.x;
  const int p0  = blockIdx.x * 128;

  // ---- stage A: gather qe rows (f32->bf16), fused sinb store
  {
    const int r = tid >> 1, h = tid & 1;
    const long base = (long)q_data[p0 + r] * DKN + h * 64;
    #pragma unroll
    for (int g = 0; g < 8; ++g) {
      const int k0 = h * 64 + g * 8;
      const float4 fa = *(const float4*)(q_table + base + g * 8);
      const float4 fb = *(const float4*)(q_table + base + g * 8 + 4);
      uint4 pk;
      pk.x = pack2(fa.x, fa.y); pk.y = pack2(fa.z, fa.w);
      pk.z = pack2(fb.x, fb.y); pk.w = pack2(fb.z, fb.w);
      *(uint4*)(As + (k0 >> 5) * 4096 + r * 32 + (k0 & 31)) = pk;
      *(uint4*)(sin_buf + (long)(p0 + r) * DSN + DKN + k0) = pk;
    }
  }
  // ---- stage B: 160 rows x 128 k = 2560 uint4 (10/thread)
  {
    #pragma unroll
    for (int u = 0; u < 10; ++u) {
      const int f = tid + 256 * u;           // 0..2559
      const int n = f >> 4, jj = f & 15;
      *(uint4*)(Bs + (jj >> 2) * 5120 + n * 32 + (jj & 3) * 8) =
          *(const uint4*)(BqT + n * 128 + jj * 8);
    }
  }
  __syncthreads();

  const int lane = tid & 63, wave = tid >> 6;
  const int wr = (wave >> 1) * 64, wc = (wave & 1) * 80;
  const int c15 = lane & 15, q = lane >> 4;

  f32x4 acc[4][5];
  float w2v[5];
  #pragma unroll
  for (int b = 0; b < 5; ++b) {
    const int col = wc + 16 * b + c15;
    const float bv = (col < 32) ? 0.f : bdf1[col - 32];
    w2v[b] = (col < 32) ? 0.f : Wdf2[col - 32];
    #pragma unroll
    for (int a = 0; a < 4; ++a) acc[a][b] = (f32x4){bv, bv, bv, bv};
  }

  #pragma unroll
  for (int c = 0; c < 4; ++c) {
    bf16x8 af[4], bf[5];
    #pragma unroll
    for (int a = 0; a < 4; ++a)
      af[a] = *(const bf16x8*)(As + c * 4096 + (wr + 16 * a + c15) * 32 + q * 8);
    #pragma unroll
    for (int b = 0; b < 5; ++b)
      bf[b] = *(const bf16x8*)(Bs + c * 5120 + (wc + 16 * b + c15) * 32 + q * 8);
    #pragma unroll
    for (int a = 0; a < 4; ++a)
      #pragma unroll
      for (int b = 0; b < 5; ++b)
        acc[a][b] = __builtin_amdgcn_mfma_f32_16x16x32_bf16(af[a], bf[b], acc[a][b], 0, 0, 0);
  }

  // ---- softmax over cols 0..31 (waves with wc==0 only: b=0,1)
  if (wc == 0) {
    #pragma unroll
    for (int a = 0; a < 4; ++a) {
      #pragma unroll
      for (int r = 0; r < 4; ++r) {
        float s0 = acc[a][0][r], s1 = acc[a][1][r];
        float mx = fmaxf(s0, s1);
        mx = fmaxf(mx, __shfl_xor(mx, 1, 64));
        mx = fmaxf(mx, __shfl_xor(mx, 2, 64));
        mx = fmaxf(mx, __shfl_xor(mx, 4, 64));
        mx = fmaxf(mx, __shfl_xor(mx, 8, 64));
        const float e0 = __expf(s0 - mx), e1 = __expf(s1 - mx);
        float sm = e0 + e1;
        sm += __shfl_xor(sm, 1, 64);
        sm += __shfl_xor(sm, 2, 64);
        sm += __shfl_xor(sm, 4, 64);
        sm += __shfl_xor(sm, 8, 64);
        const float inv = 1.f / sm;
        const int row = p0 + wr + 16 * a + 4 * q + r;
        w_all[(long)row * MEMN + c15]      = e0 * inv;
        w_all[(long)row * MEMN + 16 + c15] = e1 * inv;
      }
    }
  }

  // ---- diff partials: tanh + W_df2 dot (w2v==0 masks attention cols)
  float sv[4][4];
  #pragma unroll
  for (int a = 0; a < 4; ++a) {
    #pragma unroll
    for (int r = 0; r < 4; ++r) {
      float s = 0.f;
      #pragma unroll
      for (int b = 0; b < 5; ++b)
        s = fmaf(tanh_fast(acc[a][b][r]), w2v[b], s);
      s += __shfl_xor(s, 1, 64);
      s += __shfl_xor(s, 2, 64);
      s += __shfl_xor(s, 4, 64);
      s += __shfl_xor(s, 8, 64);
      sv[a][r] = s;
    }
  }
  __syncthreads();               // all MFMA LDS reads done; reuse As
  float* red = (float*)As;       // 128 f32
  if ((wave & 1) && c15 == 0) {  // wc==80 waves
    #pragma unroll
    for (int a = 0; a < 4; ++a)
      #pragma unroll
      for (int r = 0; r < 4; ++r)
        red[wr + 16 * a + 4 * q + r] = sv[a][r];
  }
  __syncthreads();
  if (!(wave & 1) && c15 == 0) {
    const float bd = bdf2[0];
    #pragma unroll
    for (int a = 0; a < 4; ++a)
      #pragma unroll
      for (int r = 0; r < 4; ++r) {
        const int rr = wr + 16 * a + 4 * q + r;
        diff[p0 + rr] = sv[a][r] + red[rr] + bd;
      }
  }
}

// ============================================================
// kScan v5: col-split for occupancy + async LDS chunk staging.
// grid (2*B_N): batch = blk>>1, col half ch = blk&1 (64 cols).
// block 256: thread = (lc = tid>>2 local col, h = tid&3 rows h*8..h*8+7).
// Mv[8]; reduce = shfl_xor{1,2} (4 threads/col are same-wave: 4|64).
// Chunk (32 steps) = w full 4KB + e half 4KB + a half 4KB = 12KB, dbuf.
// e/a staged only for this block's 64 cols (128B/step segments).
// 2-step register prefetch, triple-rotated, full 32-step unroll.
// 2 blocks/CU -> 2 waves/SIMD. Junk tail reads land in chunk/pad.
// ============================================================
#define CHUNK_BYTES 12288

#define KSTAGE(K, BUF)                                                        \
  {                                                                           \
    const char* wsrc = (const char*)(w_all + (pbase + (long)(K) * 32) * MEMN);\
    const char* esrc = (const char*)(eras + (pbase + (long)(K) * 32) * DVN)   \
                       + ch * 128;                                            \
    const char* asrc = (const char*)(addb + (pbase + (long)(K) * 32) * DVN)   \
                       + ch * 128;                                            \
    char* dst = lds + (BUF) * CHUNK_BYTES;                                    \
    _Pragma("unroll")                                                         \
    for (int r = 0; r < 3; ++r) {                                             \
      const int o = (tid + r * 256) * 16;                                     \
      const char* src;                                                        \
      if (o < 4096) {                                                         \
        src = wsrc + o;                                                       \
      } else if (o < 8192) {                                                  \
        const int f = o - 4096;                                               \
        src = esrc + (f >> 7) * 256 + (f & 127);                              \
      } else {                                                                \
        const int f = o - 8192;                                               \
        src = asrc + (f >> 7) * 256 + (f & 127);                              \
      }                                                                       \
      GLOAD_LDS16(src, dst + o);                                              \
    }                                                                         \
  }

__global__ __launch_bounds__(256) void kScan(
    const float* __restrict__ w_all, const u16* __restrict__ eras,
    const u16* __restrict__ addb, const float* __restrict__ init_mem,
    u16* __restrict__ sin_buf)
{
  __shared__ __align__(16) char lds[2 * CHUNK_BYTES + 512];   // pad for junk tail
  const int tid = threadIdx.x;
  const int ch  = blockIdx.x & 1;          // column half
  const int lc  = tid >> 2;                // local col 0..63
  const int gc  = ch * 64 + lc;            // global col 0..127
  const int h   = tid & 3;                 // row group: rows h*8..h*8+7
  const long pbase = (long)(blockIdx.x >> 1) * S_N;

  float Mv[8];
  #pragma unroll
  for (int m = 0; m < 8; ++m) Mv[m] = init_mem[(h * 8 + m) * DVN + gc];

  u16* sp = sin_buf + pbase * DSN + gc;

  KSTAGE(0, 0)
  for (int k = 0; k < 16; ++k) {
    __syncthreads();                       // chunk k staged
    if (k + 1 < 16) KSTAGE(k + 1, (k + 1) & 1)

    const char*  wb  = lds + (k & 1) * CHUNK_BYTES;
    const f32x4* wl4 = (const f32x4*)wb;            // [32 steps][8 f32x4]; thread uses h*2, h*2+1
    const u16*   el  = (const u16*)(wb + 4096);     // [32][64]
    const u16*   al  = (const u16*)(wb + 8192);     // [32][64]
    const int lb = k * 32;

    f32x4 Wr[3][2];
    u16 er[3], ar[3];
    #pragma unroll
    for (int i = 0; i < 2; ++i) Wr[0][i] = wl4[h * 2 + i];
    er[0] = el[lc]; ar[0] = al[lc];
    #pragma unroll
    for (int i = 0; i < 2; ++i) Wr[1][i] = wl4[8 + h * 2 + i];
    er[1] = el[64 + lc]; ar[1] = al[64 + lc];

    #pragma unroll
    for (int s = 0; s < 32; ++s) {
      const int cur = s % 3, nx2 = (s + 2) % 3;
      // prefetch step s+2 (s>=30: junk reads, in chunk/pad, unused)
      Wr[nx2][0] = wl4[(s + 2) * 8 + h * 2];
      Wr[nx2][1] = wl4[(s + 2) * 8 + h * 2 + 1];
      er[nx2] = el[(s + 2) * 64 + lc];
      ar[nx2] = al[(s + 2) * 64 + lc];
      // compute step s
      {
        float ac0 = 0.f, ac1 = 0.f, ac2 = 0.f, ac3 = 0.f;
        #pragma unroll
        for (int i = 0; i < 2; ++i) {
          ac0 = fmaf(Wr[cur][i][0], Mv[4 * i + 0], ac0);
          ac1 = fmaf(Wr[cur][i][1], Mv[4 * i + 1], ac1);
          ac2 = fmaf(Wr[cur][i][2], Mv[4 * i + 2], ac2);
          ac3 = fmaf(Wr[cur][i][3], Mv[4 * i + 3], ac3);
        }
        float pr = (ac0 + ac1) + (ac2 + ac3);
        pr += __shfl_xor(pr, 1, 64);
        pr += __shfl_xor(pr, 2, 64);
        if (h == 0) sp[(long)(lb + s) * DSN] = f2bf(pr);
        const float ec = bf2f(er[cur]);
        const float an = -bf2f(ar[cur]);
        #pragma unroll
        for (int i = 0; i < 2; ++i) {
          #pragma unroll
          for (int j = 0; j < 4; ++j) {
            const float t = fmaf(ec, Mv[4 * i + j], an);
            Mv[4 * i + j] = fmaf(-Wr[cur][i][j], t, Mv[4 * i + j]);
          }
        }
      }
    }
  }
}

// ============================================================
// kOut: combine. grid (BSN/256), block 256. f32 output.
// ============================================================
__global__ __launch_bounds__(256) void kOut(
    const float* __restrict__ part, const float* __restrict__ diff,
    const float* __restrict__ bab2, float* __restrict__ out)
{
  const int p = blockIdx.x * 256 + threadIdx.x;
  const float ab = part[p] + part[BSN + p] + bab2[0];
  const float d  = diff[p];
  const float z  = 3.0f * ab - d;
  out[p]           = sigmoid_fast(z);
  out[BSN + p]     = ab;
  out[2 * BSN + p] = d;
  out[3 * BSN + p] = z;
}

// ============================================================
// launch
// ============================================================
extern "C" void kernel_launch(void* const* d_in, const int* in_sizes, int n_in,
                              void* d_out, int out_size, void* d_ws, size_t ws_size,
                              hipStream_t stream)
{
  const int*   q_data   = (const int*)d_in[0];
  const int*   qa_data  = (const int*)d_in[1];
  const float* q_table  = (const float*)d_in[2];
  const float* qa_table = (const float*)d_in[3];
  const float* key_mem  = (const float*)d_in[4];
  const float* init_mem = (const float*)d_in[5];
  const float* W_erase  = (const float*)d_in[6];
  const float* b_erase  = (const float*)d_in[7];
  const float* W_add    = (const float*)d_in[8];
  const float* b_add    = (const float*)d_in[9];
  const float* W_sum    = (const float*)d_in[10];
  const float* b_sum    = (const float*)d_in[11];
  const float* W_ab1    = (const float*)d_in[12];
  const float* b_ab1    = (const float*)d_in[13];
  const float* W_ab2    = (const float*)d_in[14];
  const float* b_ab2    = (const float*)d_in[15];
  const float* W_df1    = (const float*)d_in[16];
  const float* b_df1    = (const float*)d_in[17];
  const float* W_df2    = (const float*)d_in[18];
  const float* b_df2    = (const float*)d_in[19];

  // workspace layout (bytes); total 152,936,448
  char* ws = (char*)d_ws;
  float* w_all = (float*)(ws + 0);           // [BS][32] f32   16,777,216
  u16*   eras  = (u16*)(ws + 16777216);      // [BS][128] bf16 33,554,432
  u16*   addb  = (u16*)(ws + 50331648);      // [BS][128] bf16 33,554,432
  u16*   sinb  = (u16*)(ws + 83886080);      // [BS][256] bf16 67,108,864
  float* diffb = (float*)(ws + 150994944);   // [BS] f32          524,288
  float* part  = (float*)(ws + 151519232);   // [2][BS] f32     1,048,576
  u16*   WerT  = (u16*)(ws + 152567808);     // 32,768
  u16*   WaddT = (u16*)(ws + 152600576);     // 32,768
  u16*   WsumT = (u16*)(ws + 152633344);     // 131,072
  u16*   Wab1T = (u16*)(ws + 152764416);     // 131,072
  u16*   BqT   = (u16*)(ws + 152895488);     // 160x128 bf16 = 40,960
  u16*   summ  = eras;                       // summary reuses eras+addb

  kPrep<<<dim3(720), 256, 0, stream>>>(W_sum, W_ab1, W_erase, W_add, key_mem, W_df1,
                                       WsumT, Wab1T, WerT, WaddT, BqT);
  kErAdd<<<dim3(BSN / 128, 2), 256, 0, stream>>>(qa_data, qa_table, WerT, WaddT,
                                                 b_erase, b_add, eras, addb);
  kQe<<<dim3(BSN / 128), 256, 0, stream>>>(q_data, q_table, BqT, b_df1, W_df2, b_df2,
                                           w_all, diffb, sinb);
  kScan<<<dim3(B_N * 2), 256, 0, stream>>>(w_all, eras, addb, init_mem, sinb);
  kSum<<<dim3(BSN / 128, 2), 256, 0, stream>>>(sinb, WsumT, b_sum, summ);
  kAb<<<dim3(BSN / 128, 2), 256, 0, stream>>>(summ, Wab1T, b_ab1, W_ab2, part);
  kOut<<<dim3(BSN / 256), 256, 0, stream>>>(part, diffb, b_ab2, (float*)d_out);
}

// Round 12
// 353.052 us; speedup vs baseline: 1.2113x; 1.0707x over previous
//
#include <hip/hip_runtime.h>
#include <hip/hip_bf16.h>

typedef unsigned short u16;
typedef unsigned int   u32;

#define B_N   256
#define S_N   512
#define BSN   (B_N * S_N)      // 131072 positions
#define MEMN  32
#define DKN   128
#define DVN   128
#define DSN   256

typedef __attribute__((ext_vector_type(8))) short bf16x8;
typedef __attribute__((ext_vector_type(4))) float f32x4;

// ---------- helpers ----------
__device__ __forceinline__ float bf2f(u16 u) {
  union { u32 i; float f; } v; v.i = ((u32)u) << 16; return v.f;
}
__device__ __forceinline__ u16 f2bf(float f) {
  union { float f; u32 i; } v; v.f = f;
  u32 x = v.i;
  x += 0x7fffu + ((x >> 16) & 1u);   // RNE
  return (u16)(x >> 16);
}
__device__ __forceinline__ u32 pack2(float a, float b) {
  return (u32)f2bf(a) | ((u32)f2bf(b) << 16);
}
__device__ __forceinline__ float sigmoid_fast(float x) { return 1.f / (1.f + __expf(-x)); }
__device__ __forceinline__ float tanh_fast(float x)    { return 1.f - 2.f / (__expf(2.f * x) + 1.f); }

#define GLOAD_LDS16(g, l)                                         \
  __builtin_amdgcn_global_load_lds(                               \
      (const __attribute__((address_space(1))) void*)(g),         \
      (__attribute__((address_space(3))) void*)(l), 16, 0, 0)

// ============================================================
// kPrep: transpose + bf16-convert weights; build concatenated BqT:
// BqT[n][k], n<32: key_mem[n][k]; n>=32: W_df1[k][n-32].   184320 elems.
// ============================================================
__global__ __launch_bounds__(256) void kPrep(
    const float* __restrict__ W_sum, const float* __restrict__ W_ab1,
    const float* __restrict__ W_er,  const float* __restrict__ W_ad,
    const float* __restrict__ key_mem, const float* __restrict__ W_df1,
    u16* __restrict__ WsumT, u16* __restrict__ Wab1T,
    u16* __restrict__ WerT,  u16* __restrict__ WaddT,
    u16* __restrict__ BqT)
{
  int e = blockIdx.x * 256 + threadIdx.x;
  if (e < 65536) {
    const int n = e >> 8, k = e & 255;
    WsumT[e] = f2bf(W_sum[k * 256 + n]);
  } else if (e < 131072) {
    e -= 65536;
    const int n = e >> 8, k = e & 255;
    Wab1T[e] = f2bf(W_ab1[k * 256 + n]);
  } else if (e < 147456) {
    e -= 131072;
    const int n = e >> 7, k = e & 127;
    WerT[e] = f2bf(W_er[k * 128 + n]);
  } else if (e < 163840) {
    e -= 147456;
    const int n = e >> 7, k = e & 127;
    WaddT[e] = f2bf(W_ad[k * 128 + n]);
  } else if (e < 184320) {
    e -= 163840;
    const int n = e >> 7, k = e & 127;
    BqT[e] = f2bf(n < 32 ? key_mem[n * 128 + k] : W_df1[k * 128 + (n - 32)]);
  }
}

// ============================================================
// kErAdd: MFMA GEMM. out = act(qae @ W + b), W pre-transposed bf16.
// grid (BSN/128, 2), block 256 (4 waves, 64x64 tiles). y: 0=erase, 1=add.
// ============================================================
__global__ __launch_bounds__(256) void kErAdd(
    const int* __restrict__ qa_data, const float* __restrict__ qa_table,
    const u16* __restrict__ WerT, const u16* __restrict__ WaddT,
    const float* __restrict__ b_er, const float* __restrict__ b_ad,
    u16* __restrict__ eras, u16* __restrict__ addb)
{
  __shared__ __align__(16) u16 As[4 * 128 * 32];   // [chunk][m][k'] 32 KB
  __shared__ __align__(16) u16 Bs[2 * 128 * 32];   // dbuf [n][k'] 16 KB
  const int tid = threadIdx.x;
  const int p0  = blockIdx.x * 128;
  const int sel = blockIdx.y;
  const u16*   Wt = sel ? WaddT : WerT;
  const float* bb = sel ? b_ad  : b_er;
  u16*       outp = sel ? addb  : eras;

  // ---- stage A: gather 128 rows of qa_table (f32 -> bf16), chunked layout
  {
    const int r = tid >> 1, h = tid & 1;
    const long base = (long)qa_data[p0 + r] * DVN + h * 64;
    #pragma unroll
    for (int g = 0; g < 8; ++g) {
      const int k0 = h * 64 + g * 8;
      const float4 fa = *(const float4*)(qa_table + base + g * 8);
      const float4 fb = *(const float4*)(qa_table + base + g * 8 + 4);
      uint4 pk;
      pk.x = pack2(fa.x, fa.y); pk.y = pack2(fa.z, fa.w);
      pk.z = pack2(fb.x, fb.y); pk.w = pack2(fb.z, fb.w);
      *(uint4*)(As + (k0 >> 5) * 4096 + r * 32 + (k0 & 31)) = pk;
    }
  }
  // ---- stage B chunk 0
  {
    #pragma unroll
    for (int u = 0; u < 2; ++u) {
      const int f = tid + 256 * u;           // 0..511
      const int n = f >> 2, j = f & 3;
      *(uint4*)(Bs + n * 32 + j * 8) = *(const uint4*)(Wt + n * 128 + j * 8);
    }
  }
  __syncthreads();

  const int lane = tid & 63, wave = tid >> 6;
  const int wr = (wave >> 1) * 64, wc = (wave & 1) * 64;
  const int c15 = lane & 15, q = lane >> 4;

  f32x4 acc[4][4];
  #pragma unroll
  for (int b = 0; b < 4; ++b) {
    const float bv = bb[wc + 16 * b + c15];
    #pragma unroll
    for (int a = 0; a < 4; ++a) acc[a][b] = (f32x4){bv, bv, bv, bv};
  }

  for (int c = 0; c < 4; ++c) {
    const int cur = c & 1;
    uint4 st[2];
    const bool more = (c + 1 < 4);
    if (more) {
      #pragma unroll
      for (int u = 0; u < 2; ++u) {
        const int f = tid + 256 * u;
        const int n = f >> 2, j = f & 3;
        st[u] = *(const uint4*)(Wt + n * 128 + (c + 1) * 32 + j * 8);
      }
    }
    bf16x8 af[4], bf[4];
    #pragma unroll
    for (int a = 0; a < 4; ++a)
      af[a] = *(const bf16x8*)(As + c * 4096 + (wr + 16 * a + c15) * 32 + q * 8);
    #pragma unroll
    for (int b = 0; b < 4; ++b)
      bf[b] = *(const bf16x8*)(Bs + cur * 4096 + (wc + 16 * b + c15) * 32 + q * 8);
    #pragma unroll
    for (int a = 0; a < 4; ++a)
      #pragma unroll
      for (int b = 0; b < 4; ++b)
        acc[a][b] = __builtin_amdgcn_mfma_f32_16x16x32_bf16(af[a], bf[b], acc[a][b], 0, 0, 0);
    if (more) {
      #pragma unroll
      for (int u = 0; u < 2; ++u) {
        const int f = tid + 256 * u;
        const int n = f >> 2, j = f & 3;
        *(uint4*)(Bs + (cur ^ 1) * 4096 + n * 32 + j * 8) = st[u];
      }
    }
    __syncthreads();
  }

  // ---- epilogue: activation + u16 stores
  const int colb = wc + c15;
  #pragma unroll
  for (int a = 0; a < 4; ++a) {
    #pragma unroll
    for (int r = 0; r < 4; ++r) {
      const int row = p0 + wr + 16 * a + 4 * q + r;
      u16* yp = outp + (long)row * DVN + colb;
      #pragma unroll
      for (int b = 0; b < 4; ++b) {
        const float v = sel ? tanh_fast(acc[a][b][r]) : sigmoid_fast(acc[a][b][r]);
        yp[16 * b] = f2bf(v);
      }
    }
  }
}

// ============================================================
// kSum: MFMA GEMM. summary = tanh(sin @ W_sum + b). K=256 (8 chunks).
// grid (BSN/128, 2: col half). LDS: A 64KB + B 16KB = 80KB.
// ============================================================
__global__ __launch_bounds__(256) void kSum(
    const u16* __restrict__ X, const u16* __restrict__ WsumT,
    const float* __restrict__ bias, u16* __restrict__ Y)
{
  __shared__ __align__(16) u16 As[8 * 128 * 32];   // 64 KB
  __shared__ __align__(16) u16 Bs[2 * 128 * 32];   // 16 KB
  const int tid = threadIdx.x;
  const int p0  = blockIdx.x * 128;
  const int j0  = blockIdx.y * 128;

  { // stage A (bf16 copy, chunked) — FULL K coverage: 4096 uint4
    #pragma unroll
    for (int u = 0; u < 16; ++u) {
      const int f = tid + 256 * u;           // 0..4095
      const int r = f >> 5, j = f & 31;      // r: row 0..127, j: k-octet 0..31
      const uint4 raw = *(const uint4*)(X + (long)(p0 + r) * DSN + j * 8);
      *(uint4*)(As + (j >> 2) * 4096 + r * 32 + (j & 3) * 8) = raw;
    }
  }
  { // stage B chunk 0
    #pragma unroll
    for (int u = 0; u < 2; ++u) {
      const int f = tid + 256 * u;
      const int n = f >> 2, j = f & 3;
      *(uint4*)(Bs + n * 32 + j * 8) = *(const uint4*)(WsumT + (j0 + n) * 256 + j * 8);
    }
  }
  __syncthreads();

  const int lane = tid & 63, wave = tid >> 6;
  const int wr = (wave >> 1) * 64, wc = (wave & 1) * 64;
  const int c15 = lane & 15, q = lane >> 4;

  f32x4 acc[4][4];
  #pragma unroll
  for (int b = 0; b < 4; ++b) {
    const float bv = bias[j0 + wc + 16 * b + c15];
    #pragma unroll
    for (int a = 0; a < 4; ++a) acc[a][b] = (f32x4){bv, bv, bv, bv};
  }

  for (int c = 0; c < 8; ++c) {
    const int cur = c & 1;
    uint4 st[2];
    const bool more = (c + 1 < 8);
    if (more) {
      #pragma unroll
      for (int u = 0; u < 2; ++u) {
        const int f = tid + 256 * u;
        const int n = f >> 2, j = f & 3;
        st[u] = *(const uint4*)(WsumT + (j0 + n) * 256 + (c + 1) * 32 + j * 8);
      }
    }
    bf16x8 af[4], bf[4];
    #pragma unroll
    for (int a = 0; a < 4; ++a)
      af[a] = *(const bf16x8*)(As + c * 4096 + (wr + 16 * a + c15) * 32 + q * 8);
    #pragma unroll
    for (int b = 0; b < 4; ++b)
      bf[b] = *(const bf16x8*)(Bs + cur * 4096 + (wc + 16 * b + c15) * 32 + q * 8);
    #pragma unroll
    for (int a = 0; a < 4; ++a)
      #pragma unroll
      for (int b = 0; b < 4; ++b)
        acc[a][b] = __builtin_amdgcn_mfma_f32_16x16x32_bf16(af[a], bf[b], acc[a][b], 0, 0, 0);
    if (more) {
      #pragma unroll
      for (int u = 0; u < 2; ++u) {
        const int f = tid + 256 * u;
        const int n = f >> 2, j = f & 3;
        *(uint4*)(Bs + (cur ^ 1) * 4096 + n * 32 + j * 8) = st[u];
      }
    }
    __syncthreads();
  }

  const int colb = j0 + wc + c15;
  #pragma unroll
  for (int a = 0; a < 4; ++a) {
    #pragma unroll
    for (int r = 0; r < 4; ++r) {
      const int row = p0 + wr + 16 * a + 4 * q + r;
      u16* yp = Y + (long)row * DSN + colb;
      #pragma unroll
      for (int b = 0; b < 4; ++b)
        yp[16 * b] = f2bf(tanh_fast(acc[a][b][r]));
    }
  }
}

// ============================================================
// kAb: MFMA GEMM + fused W_ab2 dot.
// ============================================================
__global__ __launch_bounds__(256) void kAb(
    const u16* __restrict__ X, const u16* __restrict__ Wab1T,
    const float* __restrict__ bias, const float* __restrict__ Wab2,
    float* __restrict__ part)
{
  __shared__ __align__(16) u16 As[8 * 128 * 32];
  __shared__ __align__(16) u16 Bs[2 * 128 * 32];
  const int tid = threadIdx.x;
  const int p0  = blockIdx.x * 128;
  const int j0  = blockIdx.y * 128;

  { // stage A — FULL K coverage: 4096 uint4
    #pragma unroll
    for (int u = 0; u < 16; ++u) {
      const int f = tid + 256 * u;
      const int r = f >> 5, j = f & 31;
      const uint4 raw = *(const uint4*)(X + (long)(p0 + r) * DSN + j * 8);
      *(uint4*)(As + (j >> 2) * 4096 + r * 32 + (j & 3) * 8) = raw;
    }
  }
  {
    #pragma unroll
    for (int u = 0; u < 2; ++u) {
      const int f = tid + 256 * u;
      const int n = f >> 2, j = f & 3;
      *(uint4*)(Bs + n * 32 + j * 8) = *(const uint4*)(Wab1T + (j0 + n) * 256 + j * 8);
    }
  }
  __syncthreads();

  const int lane = tid & 63, wave = tid >> 6;
  const int wr = (wave >> 1) * 64, wc = (wave & 1) * 64;
  const int c15 = lane & 15, q = lane >> 4;

  f32x4 acc[4][4];
  float w2v[4];
  #pragma unroll
  for (int b = 0; b < 4; ++b) {
    const int col = j0 + wc + 16 * b + c15;
    const float bv = bias[col];
    w2v[b] = Wab2[col];
    #pragma unroll
    for (int a = 0; a < 4; ++a) acc[a][b] = (f32x4){bv, bv, bv, bv};
  }

  for (int c = 0; c < 8; ++c) {
    const int cur = c & 1;
    uint4 st[2];
    const bool more = (c + 1 < 8);
    if (more) {
      #pragma unroll
      for (int u = 0; u < 2; ++u) {
        const int f = tid + 256 * u;
        const int n = f >> 2, j = f & 3;
        st[u] = *(const uint4*)(Wab1T + (j0 + n) * 256 + (c + 1) * 32 + j * 8);
      }
    }
    bf16x8 af[4], bf[4];
    #pragma unroll
    for (int a = 0; a < 4; ++a)
      af[a] = *(const bf16x8*)(As + c * 4096 + (wr + 16 * a + c15) * 32 + q * 8);
    #pragma unroll
    for (int b = 0; b < 4; ++b)
      bf[b] = *(const bf16x8*)(Bs + cur * 4096 + (wc + 16 * b + c15) * 32 + q * 8);
    #pragma unroll
    for (int a = 0; a < 4; ++a)
      #pragma unroll
      for (int b = 0; b < 4; ++b)
        acc[a][b] = __builtin_amdgcn_mfma_f32_16x16x32_bf16(af[a], bf[b], acc[a][b], 0, 0, 0);
    if (more) {
      #pragma unroll
      for (int u = 0; u < 2; ++u) {
        const int f = tid + 256 * u;
        const int n = f >> 2, j = f & 3;
        *(uint4*)(Bs + (cur ^ 1) * 4096 + n * 32 + j * 8) = st[u];
      }
    }
    __syncthreads();   // final barrier also fences Bs reuse below
  }

  // ---- epilogue: tanh, dot with W_ab2, reduce 16 col-lanes, pair waves
  float sv[4][4];
  #pragma unroll
  for (int a = 0; a < 4; ++a) {
    #pragma unroll
    for (int r = 0; r < 4; ++r) {
      float s = 0.f;
      #pragma unroll
      for (int b = 0; b < 4; ++b)
        s = fmaf(tanh_fast(acc[a][b][r]), w2v[b], s);
      s += __shfl_xor(s, 1, 64);
      s += __shfl_xor(s, 2, 64);
      s += __shfl_xor(s, 4, 64);
      s += __shfl_xor(s, 8, 64);
      sv[a][r] = s;
    }
  }
  float* red = (float*)Bs;   // 128 f32, reuse (fenced by loop's last barrier)
  if ((wave & 1) && c15 == 0) {
    #pragma unroll
    for (int a = 0; a < 4; ++a)
      #pragma unroll
      for (int r = 0; r < 4; ++r)
        red[wr + 16 * a + 4 * q + r] = sv[a][r];
  }
  __syncthreads();
  if (!(wave & 1) && c15 == 0) {
    #pragma unroll
    for (int a = 0; a < 4; ++a)
      #pragma unroll
      for (int r = 0; r < 4; ++r) {
        const int rr = wr + 16 * a + 4 * q + r;
        part[(long)blockIdx.y * BSN + p0 + rr] = sv[a][r] + red[rr];
      }
  }
}

// ============================================================
// kQe (MFMA): one GEMM qe[128x128] @ BqT^T[128x160] per block.
// cols 0..31 = attention scores -> softmax -> w_all
// cols 32..159 = df hidden -> tanh -> dot W_df2 -> diff
// qe -> sinb copy fused into A staging.
// ============================================================
__global__ __launch_bounds__(256) void kQe(
    const int* __restrict__ q_data, const float* __restrict__ q_table,
    const u16* __restrict__ BqT,
    const float* __restrict__ bdf1, const float* __restrict__ Wdf2,
    const float* __restrict__ bdf2,
    float* __restrict__ w_all, float* __restrict__ diff,
    u16* __restrict__ sin_buf)
{
  __shared__ __align__(16) u16 As[4 * 128 * 32];   // 32 KB [chunk][row][k']
  __shared__ __align__(16) u16 Bs[4 * 160 * 32];   // 40 KB [chunk][n][k']
  const int tid = threadIdx.x;
  const int p0  = blockIdx.x * 128;

  // ---- stage A: gather qe rows (f32->bf16), fused sinb store
  {
    const int r = tid >> 1, h = tid & 1;
    const long base = (long)q_data[p0 + r] * DKN + h * 64;
    #pragma unroll
    for (int g = 0; g < 8; ++g) {
      const int k0 = h * 64 + g * 8;
      const float4 fa = *(const float4*)(q_table + base + g * 8);
      const float4 fb = *(const float4*)(q_table + base + g * 8 + 4);
      uint4 pk;
      pk.x = pack2(fa.x, fa.y); pk.y = pack2(fa.z, fa.w);
      pk.z = pack2(fb.x, fb.y); pk.w = pack2(fb.z, fb.w);
      *(uint4*)(As + (k0 >> 5) * 4096 + r * 32 + (k0 & 31)) = pk;
      *(uint4*)(sin_buf + (long)(p0 + r) * DSN + DKN + k0) = pk;
    }
  }
  // ---- stage B: 160 rows x 128 k = 2560 uint4 (10/thread)
  {
    #pragma unroll
    for (int u = 0; u < 10; ++u) {
      const int f = tid + 256 * u;           // 0..2559
      const int n = f >> 4, jj = f & 15;
      *(uint4*)(Bs + (jj >> 2) * 5120 + n * 32 + (jj & 3) * 8) =
          *(const uint4*)(BqT + n * 128 + jj * 8);
    }
  }
  __syncthreads();

  const int lane = tid & 63, wave = tid >> 6;
  const int wr = (wave >> 1) * 64, wc = (wave & 1) * 80;
  const int c15 = lane & 15, q = lane >> 4;

  f32x4 acc[4][5];
  float w2v[5];
  #pragma unroll
  for (int b = 0; b < 5; ++b) {
    const int col = wc + 16 * b + c15;
    const float bv = (col < 32) ? 0.f : bdf1[col - 32];
    w2v[b] = (col < 32) ? 0.f : Wdf2[col - 32];
    #pragma unroll
    for (int a = 0; a < 4; ++a) acc[a][b] = (f32x4){bv, bv, bv, bv};
  }

  #pragma unroll
  for (int c = 0; c < 4; ++c) {
    bf16x8 af[4], bf[5];
    #pragma unroll
    for (int a = 0; a < 4; ++a)
      af[a] = *(const bf16x8*)(As + c * 4096 + (wr + 16 * a + c15) * 32 + q * 8);
    #pragma unroll
    for (int b = 0; b < 5; ++b)
      bf[b] = *(const bf16x8*)(Bs + c * 5120 + (wc + 16 * b + c15) * 32 + q * 8);
    #pragma unroll
    for (int a = 0; a < 4; ++a)
      #pragma unroll
      for (int b = 0; b < 5; ++b)
        acc[a][b] = __builtin_amdgcn_mfma_f32_16x16x32_bf16(af[a], bf[b], acc[a][b], 0, 0, 0);
  }

  // ---- softmax over cols 0..31 (waves with wc==0 only: b=0,1)
  if (wc == 0) {
    #pragma unroll
    for (int a = 0; a < 4; ++a) {
      #pragma unroll
      for (int r = 0; r < 4; ++r) {
        float s0 = acc[a][0][r], s1 = acc[a][1][r];
        float mx = fmaxf(s0, s1);
        mx = fmaxf(mx, __shfl_xor(mx, 1, 64));
        mx = fmaxf(mx, __shfl_xor(mx, 2, 64));
        mx = fmaxf(mx, __shfl_xor(mx, 4, 64));
        mx = fmaxf(mx, __shfl_xor(mx, 8, 64));
        const float e0 = __expf(s0 - mx), e1 = __expf(s1 - mx);
        float sm = e0 + e1;
        sm += __shfl_xor(sm, 1, 64);
        sm += __shfl_xor(sm, 2, 64);
        sm += __shfl_xor(sm, 4, 64);
        sm += __shfl_xor(sm, 8, 64);
        const float inv = 1.f / sm;
        const int row = p0 + wr + 16 * a + 4 * q + r;
        w_all[(long)row * MEMN + c15]      = e0 * inv;
        w_all[(long)row * MEMN + 16 + c15] = e1 * inv;
      }
    }
  }

  // ---- diff partials: tanh + W_df2 dot (w2v==0 masks attention cols)
  float sv[4][4];
  #pragma unroll
  for (int a = 0; a < 4; ++a) {
    #pragma unroll
    for (int r = 0; r < 4; ++r) {
      float s = 0.f;
      #pragma unroll
      for (int b = 0; b < 5; ++b)
        s = fmaf(tanh_fast(acc[a][b][r]), w2v[b], s);
      s += __shfl_xor(s, 1, 64);
      s += __shfl_xor(s, 2, 64);
      s += __shfl_xor(s, 4, 64);
      s += __shfl_xor(s, 8, 64);
      sv[a][r] = s;
    }
  }
  __syncthreads();               // all MFMA LDS reads done; reuse As
  float* red = (float*)As;       // 128 f32
  if ((wave & 1) && c15 == 0) {  // wc==80 waves
    #pragma unroll
    for (int a = 0; a < 4; ++a)
      #pragma unroll
      for (int r = 0; r < 4; ++r)
        red[wr + 16 * a + 4 * q + r] = sv[a][r];
  }
  __syncthreads();
  if (!(wave & 1) && c15 == 0) {
    const float bd = bdf2[0];
    #pragma unroll
    for (int a = 0; a < 4; ++a)
      #pragma unroll
      for (int r = 0; r < 4; ++r) {
        const int rr = wr + 16 * a + 4 * q + r;
        diff[p0 + rr] = sv[a][r] + red[rr] + bd;
      }
  }
}

// ============================================================
// kScan v6: col-split + async LDS chunk staging + DEFERRED reduction.
// Round-11 finding: per-step __shfl forces lgkmcnt(0) drains that
// serialize each step (~472 cy invariant). Fix: no cross-lane ops in
// the step loop — each thread ds_writes its 4-row partial to an LDS
// partial buffer (fire-and-forget); reduction + f2bf + sinb store
// happen in bulk once per 32-step chunk.
// grid (2*B_N): batch = blk>>1, col half ch = blk&1.
// block 256: lc = tid>>2 (local col), h = tid&3 (rows h*8..h*8+7), Mv[8].
// LDS: dbuf 2x12KB + 512 pad + partials 32KB = 57856 B -> 2 blocks/CU.
// ============================================================
#define CHUNK_BYTES 12288
#define PB_OFF      25088     // 2*CHUNK_BYTES + 512

#define KSTAGE(K, BUF)                                                        \
  {                                                                           \
    const char* wsrc = (const char*)(w_all + (pbase + (long)(K) * 32) * MEMN);\
    const char* esrc = (const char*)(eras + (pbase + (long)(K) * 32) * DVN)   \
                       + ch * 128;                                            \
    const char* asrc = (const char*)(addb + (pbase + (long)(K) * 32) * DVN)   \
                       + ch * 128;                                            \
    char* dst = lds + (BUF) * CHUNK_BYTES;                                    \
    _Pragma("unroll")                                                         \
    for (int r = 0; r < 3; ++r) {                                             \
      const int o = (tid + r * 256) * 16;                                     \
      const char* src;                                                        \
      if (o < 4096) {                                                         \
        src = wsrc + o;                                                       \
      } else if (o < 8192) {                                                  \
        const int f = o - 4096;                                               \
        src = esrc + (f >> 7) * 256 + (f & 127);                              \
      } else {                                                                \
        const int f = o - 8192;                                               \
        src = asrc + (f >> 7) * 256 + (f & 127);                              \
      }                                                                       \
      GLOAD_LDS16(src, dst + o);                                              \
    }                                                                         \
  }

__global__ __launch_bounds__(256) void kScan(
    const float* __restrict__ w_all, const u16* __restrict__ eras,
    const u16* __restrict__ addb, const float* __restrict__ init_mem,
    u16* __restrict__ sin_buf)
{
  __shared__ __align__(16) char lds[PB_OFF + 32768];   // dbuf+pad + partials
  const int tid = threadIdx.x;
  const int ch  = blockIdx.x & 1;          // column half
  const int lc  = tid >> 2;                // local col 0..63
  const int gc  = ch * 64 + lc;            // global col 0..127
  const int h   = tid & 3;                 // row group: rows h*8..h*8+7
  const long pbase = (long)(blockIdx.x >> 1) * S_N;

  float* pb = (float*)(lds + PB_OFF);      // [32 steps][64 cols][4 h] f32

  float Mv[8];
  #pragma unroll
  for (int m = 0; m < 8; ++m) Mv[m] = init_mem[(h * 8 + m) * DVN + gc];

  // reduction-phase indexing (coalesced: 64 consecutive cols per 64 lanes)
  const int lc2  = tid & 63;
  const int sblk = tid >> 6;               // 0..3 -> steps sblk*8..sblk*8+7
  u16* sp2 = sin_buf + pbase * DSN + ch * 64 + lc2;

  KSTAGE(0, 0)
  for (int k = 0; k < 16; ++k) {
    __syncthreads();                       // chunk k staged; pb free for writes
    if (k + 1 < 16) KSTAGE(k + 1, (k + 1) & 1)

    const char*  wb  = lds + (k & 1) * CHUNK_BYTES;
    const f32x4* wl4 = (const f32x4*)wb;            // [32 steps][8 f32x4]; thread uses h*2, h*2+1
    const u16*   el  = (const u16*)(wb + 4096);     // [32][64]
    const u16*   al  = (const u16*)(wb + 8192);     // [32][64]

    f32x4 Wr[3][2];
    u16 er[3], ar[3];
    #pragma unroll
    for (int i = 0; i < 2; ++i) Wr[0][i] = wl4[h * 2 + i];
    er[0] = el[lc]; ar[0] = al[lc];
    #pragma unroll
    for (int i = 0; i < 2; ++i) Wr[1][i] = wl4[8 + h * 2 + i];
    er[1] = el[64 + lc]; ar[1] = al[64 + lc];

    #pragma unroll
    for (int s = 0; s < 32; ++s) {
      const int cur = s % 3, nx2 = (s + 2) % 3;
      // prefetch step s+2 (s>=30: junk reads, in chunk/pad, unused)
      Wr[nx2][0] = wl4[(s + 2) * 8 + h * 2];
      Wr[nx2][1] = wl4[(s + 2) * 8 + h * 2 + 1];
      er[nx2] = el[(s + 2) * 64 + lc];
      ar[nx2] = al[(s + 2) * 64 + lc];
      // compute step s — NO cross-lane ops, NO waits on results
      {
        float ac0 = 0.f, ac1 = 0.f, ac2 = 0.f, ac3 = 0.f;
        #pragma unroll
        for (int i = 0; i < 2; ++i) {
          ac0 = fmaf(Wr[cur][i][0], Mv[4 * i + 0], ac0);
          ac1 = fmaf(Wr[cur][i][1], Mv[4 * i + 1], ac1);
          ac2 = fmaf(Wr[cur][i][2], Mv[4 * i + 2], ac2);
          ac3 = fmaf(Wr[cur][i][3], Mv[4 * i + 3], ac3);
        }
        pb[s * 256 + lc * 4 + h] = (ac0 + ac1) + (ac2 + ac3);   // fire-and-forget
        const float ec = bf2f(er[cur]);
        const float an = -bf2f(ar[cur]);
        #pragma unroll
        for (int i = 0; i < 2; ++i) {
          #pragma unroll
          for (int j = 0; j < 4; ++j) {
            const float t = fmaf(ec, Mv[4 * i + j], an);
            Mv[4 * i + j] = fmaf(-Wr[cur][i][j], t, Mv[4 * i + j]);
          }
        }
      }
    }

    // ---- bulk reduction of this chunk's partials (once per 32 steps)
    __syncthreads();                       // partials visible
    const int lb = k * 32;
    #pragma unroll
    for (int r = 0; r < 8; ++r) {
      const int s = sblk * 8 + r;
      const f32x4 pv = *(const f32x4*)(pb + s * 256 + lc2 * 4);
      sp2[(long)(lb + s) * DSN] = f2bf((pv[0] + pv[1]) + (pv[2] + pv[3]));
    }
  }
}

// ============================================================
// kOut: combine. grid (BSN/256), block 256. f32 output.
// ============================================================
__global__ __launch_bounds__(256) void kOut(
    const float* __restrict__ part, const float* __restrict__ diff,
    const float* __restrict__ bab2, float* __restrict__ out)
{
  const int p = blockIdx.x * 256 + threadIdx.x;
  const float ab = part[p] + part[BSN + p] + bab2[0];
  const float d  = diff[p];
  const float z  = 3.0f * ab - d;
  out[p]           = sigmoid_fast(z);
  out[BSN + p]     = ab;
  out[2 * BSN + p] = d;
  out[3 * BSN + p] = z;
}

// ============================================================
// launch
// ============================================================
extern "C" void kernel_launch(void* const* d_in, const int* in_sizes, int n_in,
                              void* d_out, int out_size, void* d_ws, size_t ws_size,
                              hipStream_t stream)
{
  const int*   q_data   = (const int*)d_in[0];
  const int*   qa_data  = (const int*)d_in[1];
  const float* q_table  = (const float*)d_in[2];
  const float* qa_table = (const float*)d_in[3];
  const float* key_mem  = (const float*)d_in[4];
  const float* init_mem = (const float*)d_in[5];
  const float* W_erase  = (const float*)d_in[6];
  const float* b_erase  = (const float*)d_in[7];
  const float* W_add    = (const float*)d_in[8];
  const float* b_add    = (const float*)d_in[9];
  const float* W_sum    = (const float*)d_in[10];
  const float* b_sum    = (const float*)d_in[11];
  const float* W_ab1    = (const float*)d_in[12];
  const float* b_ab1    = (const float*)d_in[13];
  const float* W_ab2    = (const float*)d_in[14];
  const float* b_ab2    = (const float*)d_in[15];
  const float* W_df1    = (const float*)d_in[16];
  const float* b_df1    = (const float*)d_in[17];
  const float* W_df2    = (const float*)d_in[18];
  const float* b_df2    = (const float*)d_in[19];

  // workspace layout (bytes); total 152,936,448
  char* ws = (char*)d_ws;
  float* w_all = (float*)(ws + 0);           // [BS][32] f32   16,777,216
  u16*   eras  = (u16*)(ws + 16777216);      // [BS][128] bf16 33,554,432
  u16*   addb  = (u16*)(ws + 50331648);      // [BS][128] bf16 33,554,432
  u16*   sinb  = (u16*)(ws + 83886080);      // [BS][256] bf16 67,108,864
  float* diffb = (float*)(ws + 150994944);   // [BS] f32          524,288
  float* part  = (float*)(ws + 151519232);   // [2][BS] f32     1,048,576
  u16*   WerT  = (u16*)(ws + 152567808);     // 32,768
  u16*   WaddT = (u16*)(ws + 152600576);     // 32,768
  u16*   WsumT = (u16*)(ws + 152633344);     // 131,072
  u16*   Wab1T = (u16*)(ws + 152764416);     // 131,072
  u16*   BqT   = (u16*)(ws + 152895488);     // 160x128 bf16 = 40,960
  u16*   summ  = eras;                       // summary reuses eras+addb

  kPrep<<<dim3(720), 256, 0, stream>>>(W_sum, W_ab1, W_erase, W_add, key_mem, W_df1,
                                       WsumT, Wab1T, WerT, WaddT, BqT);
  kErAdd<<<dim3(BSN / 128, 2), 256, 0, stream>>>(qa_data, qa_table, WerT, WaddT,
                                                 b_erase, b_add, eras, addb);
  kQe<<<dim3(BSN / 128), 256, 0, stream>>>(q_data, q_table, BqT, b_df1, W_df2, b_df2,
                                           w_all, diffb, sinb);
  kScan<<<dim3(B_N * 2), 256, 0, stream>>>(w_all, eras, addb, init_mem, sinb);
  kSum<<<dim3(BSN / 128, 2), 256, 0, stream>>>(sinb, WsumT, b_sum, summ);
  kAb<<<dim3(BSN / 128, 2), 256, 0, stream>>>(summ, Wab1T, b_ab1, W_ab2, part);
  kOut<<<dim3(BSN / 256), 256, 0, stream>>>(part, diffb, b_ab2, (float*)d_out);
}